// Round 8
// baseline (3459.584 us; speedup 1.0000x reference)
//
#include <hip/hip_runtime.h>
#include <hip/hip_bf16.h>
#include <cstdint>
#include <cstddef>

#define BN_EPS 1e-3f
typedef unsigned short ushort_t;
typedef unsigned int uint_t;
typedef __attribute__((ext_vector_type(8))) short short8v;   // 8 bf16 (4 VGPRs)
typedef __attribute__((ext_vector_type(4))) float f32x4;     // MFMA C/D

// ---------- numeric helpers ----------

__device__ __forceinline__ float fast_tanh(float x) {
    float xc = fminf(fmaxf(x, -12.0f), 12.0f);
    float e = __expf(2.0f * xc);
    return (e - 1.0f) / (e + 1.0f);
}

__device__ __forceinline__ float bf2f(uint_t u) {
    return __uint_as_float(u << 16);
}
__device__ __forceinline__ ushort_t f2bf(float f) {
    union { __hip_bfloat16 h; ushort_t u; } cv;
    cv.h = __float2bfloat16(f);   // RNE
    return cv.u;
}

// split 8 f32 -> 8 bf16 hi + 8 bf16 lo (lo = bf16(x - hi)), packed 16B each
__device__ __forceinline__ void split8(const float* f, uint4& h, uint4& lo) {
    uint_t hh[8], ll[8];
    #pragma unroll
    for (int j = 0; j < 8; ++j) {
        float x = f[j];
        ushort_t xh = f2bf(x);
        float xr = x - bf2f(xh);
        hh[j] = xh;
        ll[j] = f2bf(xr);
    }
    h  = make_uint4(hh[0] | (hh[1] << 16), hh[2] | (hh[3] << 16),
                    hh[4] | (hh[5] << 16), hh[6] | (hh[7] << 16));
    lo = make_uint4(ll[0] | (ll[1] << 16), ll[2] | (ll[3] << 16),
                    ll[4] | (ll[5] << 16), ll[6] | (ll[7] << 16));
}

// ---------- counting sort of atoms by membership (ascending) ----------

__global__ void k_zero_bins(int* __restrict__ binCnt, int* __restrict__ binFill) {
    int t = blockIdx.x * 256 + threadIdx.x;
    if (t < 40000) { binCnt[t] = 0; binFill[t] = 0; }
}

__global__ void k_hist(const int* __restrict__ memb, int* __restrict__ binCnt) {
    int t = blockIdx.x * 256 + threadIdx.x;
    if (t < 1000000) atomicAdd(&binCnt[memb[t]], 1);
}

__global__ __launch_bounds__(1024)
void k_scan(const int* __restrict__ binCnt, int* __restrict__ binBase) {
    __shared__ int part[1024];
    const int t = threadIdx.x;
    const int base = t * 40;
    int local[40];
    int s = 0;
    #pragma unroll
    for (int j = 0; j < 40; ++j) {
        int idx = base + j;
        int c = (idx < 40000) ? binCnt[idx] : 0;
        local[j] = s;
        s += c;
    }
    part[t] = s;
    __syncthreads();
    for (int off = 1; off < 1024; off <<= 1) {
        int v = (t >= off) ? part[t - off] : 0;
        __syncthreads();
        part[t] += v;
        __syncthreads();
    }
    int add = (t > 0) ? part[t - 1] : 0;
    #pragma unroll
    for (int j = 0; j < 40; ++j) {
        int idx = base + j;
        if (idx < 40000) binBase[idx] = add + local[j];
    }
}

__global__ void k_scatter(const int* __restrict__ memb, const int* __restrict__ binBase,
                          int* __restrict__ binFill, int* __restrict__ perm) {
    int t = blockIdx.x * 256 + threadIdx.x;
    if (t < 1000000) {
        int m = memb[t];
        int pos = binBase[m] + atomicAdd(&binFill[m], 1);
        perm[pos] = t;
    }
}

// ---------- subtile metadata: 125000 subtiles of 8 sorted rows ----------

__global__ void k_meta(const int* __restrict__ memb, const int* __restrict__ perm,
                       int* __restrict__ firstSeg, int* __restrict__ segCnt) {
    int t = blockIdx.x * 256 + threadIdx.x;
    if (t < 125000) {
        int f = memb[perm[8 * t]];
        int l = memb[perm[8 * t + 7]];
        firstSeg[t] = f;
        segCnt[t] = l - f + 1;
    }
}

__global__ __launch_bounds__(1024)
void k_scan2(const int* __restrict__ segCnt, int* __restrict__ cumSeg) {
    __shared__ int part[1024];
    const int t = threadIdx.x;
    const int base = t * 123;
    int s = 0;
    for (int j = 0; j < 123; ++j) {
        int idx = base + j;
        if (idx < 125000) s += segCnt[idx];
    }
    part[t] = s;
    __syncthreads();
    for (int off = 1; off < 1024; off <<= 1) {
        int v = (t >= off) ? part[t - off] : 0;
        __syncthreads();
        part[t] += v;
        __syncthreads();
    }
    int run = (t > 0) ? part[t - 1] : 0;
    for (int j = 0; j < 123; ++j) {
        int idx = base + j;
        if (idx < 125000) { cumSeg[idx] = run; run += segCnt[idx]; }
    }
}

// ---------- W fragment prep: dense [128][256] ----------
// fid = (tn*4 + ks)*64 + lane; lane j holds W[ks*32 + (lane>>4)*8 + j][tn*16 + (lane&15)]

__global__ void k_prepW(const float* __restrict__ W,
                        ushort_t* __restrict__ Bh, ushort_t* __restrict__ Bl) {
    int idx = blockIdx.x * 256 + threadIdx.x;
    if (idx >= 4096) return;
    int l = idx & 63, g = idx >> 6;       // g = tn*4 + ks
    int tn = g >> 2, ks = g & 3;
    int n = tn * 16 + (l & 15);
    int k0 = ks * 32 + (l >> 4) * 8;
    float f[8];
    #pragma unroll
    for (int j = 0; j < 8; ++j) f[j] = W[(size_t)(k0 + j) * 256 + n];
    uint4 h, lo; split8(f, h, lo);
    *(uint4*)(Bh + (size_t)idx * 8) = h;
    *(uint4*)(Bl + (size_t)idx * 8) = lo;
}

// ---------- W fragment prep: gc2's 9 matrices [128][128] (5 self + 4 rel) ----------
// per matrix: 2048 frags (tn 0..7, ks 0..3, lane 0..63).

__global__ void k_prepW2(const float* __restrict__ Ws5, const float* __restrict__ Wr4,
                         ushort_t* __restrict__ Fh, ushort_t* __restrict__ Fl) {
    int idx = blockIdx.x * 256 + threadIdx.x;   // [0, 9*2048)
    if (idx >= 18432) return;
    int mat = idx >> 11;
    int fid = idx & 2047;
    int l = fid & 63, g = fid >> 6;
    int tn = g >> 2, ks = g & 3;
    int n = tn * 16 + (l & 15);
    int k0 = ks * 32 + (l >> 4) * 8;
    const float* W = (mat < 5) ? (Ws5 + (size_t)mat * 16384)
                               : (Wr4 + (size_t)(mat - 5) * 16384);
    float f[8];
    #pragma unroll
    for (int j = 0; j < 8; ++j) f[j] = W[(size_t)(k0 + j) * 128 + n];
    uint4 h, lo; split8(f, h, lo);
    *(uint4*)(Fh + (size_t)idx * 8) = h;
    *(uint4*)(Fl + (size_t)idx * 8) = lo;
}

// ---------- W fragment prep: gc1's 9 matrices [75][128], K padded to 96 ----------
// per matrix: 1536 frags (tn 0..7, ks 0..2, lane 0..63); k >= 75 -> 0.

__global__ void k_prepW1(const float* __restrict__ Ws5, const float* __restrict__ Wr4,
                         ushort_t* __restrict__ Fh, ushort_t* __restrict__ Fl) {
    int idx = blockIdx.x * 256 + threadIdx.x;   // [0, 9*1536)
    if (idx >= 13824) return;
    int mat = idx / 1536;
    int fid = idx - mat * 1536;
    int l = fid & 63, g = fid >> 6;             // g = tn*3 + ks
    int tn = g / 3, ks = g - tn * 3;
    int n = tn * 16 + (l & 15);
    int k0 = ks * 32 + (l >> 4) * 8;
    const float* W = (mat < 5) ? (Ws5 + (size_t)mat * 9600)
                               : (Wr4 + (size_t)(mat - 5) * 9600);
    float f[8];
    #pragma unroll
    for (int j = 0; j < 8; ++j)
        f[j] = (k0 + j < 75) ? W[(size_t)(k0 + j) * 128 + n] : 0.0f;
    uint4 h, lo; split8(f, h, lo);
    *(uint4*)(Fh + (size_t)idx * 8) = h;
    *(uint4*)(Fl + (size_t)idx * 8) = lo;
}

// ---------- gc1 via MFMA split-bf16 (tanh + bn1 fused), K=75 padded to 96 ----------
// Same structure as gc2m: 64 atoms x 128 cols, 4 waves, wave owns n-tiles
// {w, w+4}. 3 k-steps. Scalar staging with per-element split (rows are 75 f32,
// not vector-alignable). Logical chunks 9..11 hold k=72..95 incl. zeros.

template<int DEG>
__global__ __launch_bounds__(256)
void k_gc1m(const float* __restrict__ X, const int* __restrict__ adj,
            const ushort_t* __restrict__ Wsh, const ushort_t* __restrict__ Wsl,
            const ushort_t* __restrict__ Wrh, const ushort_t* __restrict__ Wrl,
            const float* __restrict__ bias,
            const float* __restrict__ bg, const float* __restrict__ bb,
            const float* __restrict__ bm, const float* __restrict__ bv,
            float* __restrict__ Out, int start, int count)
{
    __shared__ __align__(16) ushort_t Sh[64 * 128];
    __shared__ __align__(16) ushort_t Sl[64 * 128];
    __shared__ __align__(16) ushort_t Nh[(DEG > 0) ? 64 * 128 : 8];
    __shared__ __align__(16) ushort_t Nl[(DEG > 0) ? 64 * 128 : 8];

    const int tid = threadIdx.x;
    const int tileBase = blockIdx.x * 64;

    // stage k=0..95 (zeros for k>=75 or ga>=count); swizzled scalar writes
    for (int idx = tid; idx < 64 * 96; idx += 256) {
        int a = idx / 96;
        int k = idx - a * 96;
        int ga = tileBase + a;
        float sv = 0.0f, nv = 0.0f;
        if (k < 75 && ga < count) {
            sv = X[(size_t)(start + ga) * 75 + k];
            if constexpr (DEG > 0) {
                #pragma unroll
                for (int j = 0; j < DEG; ++j) {
                    int nb = adj[(size_t)ga * DEG + j];
                    nv += X[(size_t)nb * 75 + k];
                }
            }
        }
        int pos = a * 128 + (((k >> 3) ^ (a & 15)) << 3) + (k & 7);
        ushort_t svh = f2bf(sv);
        Sh[pos] = svh;
        Sl[pos] = f2bf(sv - bf2f(svh));
        if constexpr (DEG > 0) {
            ushort_t nvh = f2bf(nv);
            Nh[pos] = nvh;
            Nl[pos] = f2bf(nv - bf2f(nvh));
        }
    }
    __syncthreads();

    const int w = tid >> 6, l = tid & 63;
    const int lm = l & 15, lq = l >> 4;

    f32x4 acc[4][2];
    #pragma unroll
    for (int rt = 0; rt < 4; ++rt)
        #pragma unroll
        for (int ti = 0; ti < 2; ++ti)
            acc[rt][ti] = (f32x4){0.f, 0.f, 0.f, 0.f};

    for (int ks = 0; ks < 3; ++ks) {
        short8v ash[4], asl[4], anh[4], anl[4];
        #pragma unroll
        for (int rt = 0; rt < 4; ++rt) {
            int a = rt * 16 + lm;
            int cs = (ks * 4 + lq) ^ lm;
            ash[rt] = *(const short8v*)(Sh + a * 128 + cs * 8);
            asl[rt] = *(const short8v*)(Sl + a * 128 + cs * 8);
            if constexpr (DEG > 0) {
                anh[rt] = *(const short8v*)(Nh + a * 128 + cs * 8);
                anl[rt] = *(const short8v*)(Nl + a * 128 + cs * 8);
            }
        }
        #pragma unroll
        for (int ti = 0; ti < 2; ++ti) {
            int fid = ((w + ti * 4) * 3 + ks) * 64 + l;
            short8v bh = *(const short8v*)(Wsh + (size_t)fid * 8);
            short8v bl = *(const short8v*)(Wsl + (size_t)fid * 8);
            #pragma unroll
            for (int rt = 0; rt < 4; ++rt) {
                acc[rt][ti] = __builtin_amdgcn_mfma_f32_16x16x32_bf16(ash[rt], bh, acc[rt][ti], 0, 0, 0);
                acc[rt][ti] = __builtin_amdgcn_mfma_f32_16x16x32_bf16(asl[rt], bh, acc[rt][ti], 0, 0, 0);
                acc[rt][ti] = __builtin_amdgcn_mfma_f32_16x16x32_bf16(ash[rt], bl, acc[rt][ti], 0, 0, 0);
            }
            if constexpr (DEG > 0) {
                short8v rh = *(const short8v*)(Wrh + (size_t)fid * 8);
                short8v rl = *(const short8v*)(Wrl + (size_t)fid * 8);
                #pragma unroll
                for (int rt = 0; rt < 4; ++rt) {
                    acc[rt][ti] = __builtin_amdgcn_mfma_f32_16x16x32_bf16(anh[rt], rh, acc[rt][ti], 0, 0, 0);
                    acc[rt][ti] = __builtin_amdgcn_mfma_f32_16x16x32_bf16(anl[rt], rh, acc[rt][ti], 0, 0, 0);
                    acc[rt][ti] = __builtin_amdgcn_mfma_f32_16x16x32_bf16(anh[rt], rl, acc[rt][ti], 0, 0, 0);
                }
            }
        }
    }

    // epilogue: +bias, tanh, bn1; direct stores (C/D: col=lm, row=lq*4+r)
    #pragma unroll
    for (int ti = 0; ti < 2; ++ti) {
        int cc = (w + ti * 4) * 16 + lm;
        float bz = bias[cc];
        float s = bg[cc] * rsqrtf(bv[cc] + BN_EPS);
        float sb = bb[cc] - bm[cc] * s;
        #pragma unroll
        for (int rt = 0; rt < 4; ++rt) {
            #pragma unroll
            for (int r = 0; r < 4; ++r) {
                int ga = tileBase + rt * 16 + lq * 4 + r;
                if (ga < count)
                    Out[(size_t)(start + ga) * 128 + cc] =
                        fast_tanh(acc[rt][ti][r] + bz) * s + sb;
            }
        }
    }
}

// ---------- gc2 via MFMA split-bf16 (tanh + bn1 fused) ----------

template<int DEG>
__global__ __launch_bounds__(256)
void k_gc2m(const float* __restrict__ X, const int* __restrict__ adj,
            const ushort_t* __restrict__ Wsh, const ushort_t* __restrict__ Wsl,
            const ushort_t* __restrict__ Wrh, const ushort_t* __restrict__ Wrl,
            const float* __restrict__ bias,
            const float* __restrict__ bg, const float* __restrict__ bb,
            const float* __restrict__ bm, const float* __restrict__ bv,
            float* __restrict__ Out, int start, int count)
{
    __shared__ __align__(16) ushort_t Sh[64 * 128];
    __shared__ __align__(16) ushort_t Sl[64 * 128];
    __shared__ __align__(16) ushort_t Nh[(DEG > 0) ? 64 * 128 : 8];
    __shared__ __align__(16) ushort_t Nl[(DEG > 0) ? 64 * 128 : 8];

    const int tid = threadIdx.x;
    const int tileBase = blockIdx.x * 64;

    for (int idx = tid; idx < 1024; idx += 256) {
        int a = idx >> 4, c = idx & 15;
        int ga = tileBase + a;
        float fs[8] = {0, 0, 0, 0, 0, 0, 0, 0};
        float fn[8] = {0, 0, 0, 0, 0, 0, 0, 0};
        if (ga < count) {
            const float* row = X + (size_t)(start + ga) * 128 + c * 8;
            *(float4*)(&fs[0]) = *(const float4*)row;
            *(float4*)(&fs[4]) = *(const float4*)(row + 4);
            if constexpr (DEG > 0) {
                #pragma unroll
                for (int j = 0; j < DEG; ++j) {
                    int nb = adj[(size_t)ga * DEG + j];
                    const float* nr = X + (size_t)nb * 128 + c * 8;
                    float4 q0 = *(const float4*)nr;
                    float4 q1 = *(const float4*)(nr + 4);
                    fn[0] += q0.x; fn[1] += q0.y; fn[2] += q0.z; fn[3] += q0.w;
                    fn[4] += q1.x; fn[5] += q1.y; fn[6] += q1.z; fn[7] += q1.w;
                }
            }
        }
        int cs = c ^ (a & 15);
        uint4 h, lo;
        split8(fs, h, lo);
        *(uint4*)(Sh + a * 128 + cs * 8) = h;
        *(uint4*)(Sl + a * 128 + cs * 8) = lo;
        if constexpr (DEG > 0) {
            split8(fn, h, lo);
            *(uint4*)(Nh + a * 128 + cs * 8) = h;
            *(uint4*)(Nl + a * 128 + cs * 8) = lo;
        }
    }
    __syncthreads();

    const int w = tid >> 6, l = tid & 63;
    const int lm = l & 15, lq = l >> 4;

    f32x4 acc[4][2];
    #pragma unroll
    for (int rt = 0; rt < 4; ++rt)
        #pragma unroll
        for (int ti = 0; ti < 2; ++ti)
            acc[rt][ti] = (f32x4){0.f, 0.f, 0.f, 0.f};

    for (int ks = 0; ks < 4; ++ks) {
        short8v ash[4], asl[4], anh[4], anl[4];
        #pragma unroll
        for (int rt = 0; rt < 4; ++rt) {
            int a = rt * 16 + lm;
            int cs = (ks * 4 + lq) ^ lm;
            ash[rt] = *(const short8v*)(Sh + a * 128 + cs * 8);
            asl[rt] = *(const short8v*)(Sl + a * 128 + cs * 8);
            if constexpr (DEG > 0) {
                anh[rt] = *(const short8v*)(Nh + a * 128 + cs * 8);
                anl[rt] = *(const short8v*)(Nl + a * 128 + cs * 8);
            }
        }
        #pragma unroll
        for (int ti = 0; ti < 2; ++ti) {
            int fid = ((w + ti * 4) * 4 + ks) * 64 + l;
            short8v bh = *(const short8v*)(Wsh + (size_t)fid * 8);
            short8v bl = *(const short8v*)(Wsl + (size_t)fid * 8);
            #pragma unroll
            for (int rt = 0; rt < 4; ++rt) {
                acc[rt][ti] = __builtin_amdgcn_mfma_f32_16x16x32_bf16(ash[rt], bh, acc[rt][ti], 0, 0, 0);
                acc[rt][ti] = __builtin_amdgcn_mfma_f32_16x16x32_bf16(asl[rt], bh, acc[rt][ti], 0, 0, 0);
                acc[rt][ti] = __builtin_amdgcn_mfma_f32_16x16x32_bf16(ash[rt], bl, acc[rt][ti], 0, 0, 0);
            }
            if constexpr (DEG > 0) {
                short8v rh = *(const short8v*)(Wrh + (size_t)fid * 8);
                short8v rl = *(const short8v*)(Wrl + (size_t)fid * 8);
                #pragma unroll
                for (int rt = 0; rt < 4; ++rt) {
                    acc[rt][ti] = __builtin_amdgcn_mfma_f32_16x16x32_bf16(anh[rt], rh, acc[rt][ti], 0, 0, 0);
                    acc[rt][ti] = __builtin_amdgcn_mfma_f32_16x16x32_bf16(anl[rt], rh, acc[rt][ti], 0, 0, 0);
                    acc[rt][ti] = __builtin_amdgcn_mfma_f32_16x16x32_bf16(anh[rt], rl, acc[rt][ti], 0, 0, 0);
                }
            }
        }
    }

    #pragma unroll
    for (int ti = 0; ti < 2; ++ti) {
        int cc = (w + ti * 4) * 16 + lm;
        float bz = bias[cc];
        float s = bg[cc] * rsqrtf(bv[cc] + BN_EPS);
        float sb = bb[cc] - bm[cc] * s;
        #pragma unroll
        for (int rt = 0; rt < 4; ++rt) {
            #pragma unroll
            for (int r = 0; r < 4; ++r) {
                int ga = tileBase + rt * 16 + lq * 4 + r;
                if (ga < count)
                    Out[(size_t)(start + ga) * 128 + cc] =
                        fast_tanh(acc[rt][ti][r] + bz) * s + sb;
            }
        }
    }
}

// ---------- graph pool (elementwise max over self + neighbors), f32 ----------

template<int DEG>
__global__ void k_pool(const float* __restrict__ X, const int* __restrict__ adj,
                       float* __restrict__ Out, int start, int count)
{
    int t = blockIdx.x * 256 + threadIdx.x;
    int a = t >> 5;
    if (a >= count) return;
    int c4 = t & 31;
    const float4* X4 = (const float4*)X;
    float4 v = X4[(size_t)(start + a) * 32 + c4];
    #pragma unroll
    for (int j = 0; j < DEG; ++j) {
        int nb = adj[(size_t)a * DEG + j];
        float4 q = X4[(size_t)nb * 32 + c4];
        v.x = fmaxf(v.x, q.x); v.y = fmaxf(v.y, q.y);
        v.z = fmaxf(v.z, q.z); v.w = fmaxf(v.w, q.w);
    }
    ((float4*)Out)[(size_t)(start + a) * 32 + c4] = v;
}

// ---------- dense via MFMA split-bf16 (tanh + bn3) + subtile partials ----------

__global__ __launch_bounds__(256)
void k_dense_mfma(const float* __restrict__ X,      // [1M][128] (pool2 out)
                  const int*   __restrict__ memb,
                  const int*   __restrict__ perm,    // membership-ascending
                  const int*   __restrict__ cumSeg,  // [125000]
                  const ushort_t* __restrict__ Bh,   // W frag hi [4096][8]
                  const ushort_t* __restrict__ Bl,   // W frag lo
                  const float* __restrict__ bias,    // [256]
                  const float* __restrict__ bg, const float* __restrict__ bb,
                  const float* __restrict__ bm, const float* __restrict__ bv,
                  float* __restrict__ partials)
{
    __shared__ __align__(16) char smem[33792];   // Ah[16KB]+Al[16KB] / Yt[64][132]f32
    __shared__ int sM[64];
    __shared__ int sP[64];
    ushort_t* Ah = (ushort_t*)smem;
    ushort_t* Al = (ushort_t*)(smem + 16384);
    float*    Yt = (float*)smem;

    const int tid = threadIdx.x;
    const int tileBase = blockIdx.x * 64;
    if (tid < 64) {
        int p = perm[tileBase + tid];
        sP[tid] = p;
        sM[tid] = memb[p];
    }
    __syncthreads();

    for (int idx = tid; idx < 1024; idx += 256) {
        int a = idx >> 4, c = idx & 15;
        const float* row = X + (size_t)sP[a] * 128 + c * 8;
        float f[8];
        *(float4*)(&f[0]) = *(const float4*)row;
        *(float4*)(&f[4]) = *(const float4*)(row + 4);
        uint4 h, lo; split8(f, h, lo);
        int cs = c ^ (a & 15);
        *(uint4*)(Ah + a * 128 + cs * 8) = h;
        *(uint4*)(Al + a * 128 + cs * 8) = lo;
    }
    __syncthreads();

    const int w = tid >> 6, l = tid & 63;
    const int lm = l & 15, lq = l >> 4;

    f32x4 acc[4][4];
    #pragma unroll
    for (int rt = 0; rt < 4; ++rt)
        #pragma unroll
        for (int ti = 0; ti < 4; ++ti)
            acc[rt][ti] = (f32x4){0.f, 0.f, 0.f, 0.f};

    for (int ks = 0; ks < 4; ++ks) {
        short8v ah[4], al[4];
        #pragma unroll
        for (int rt = 0; rt < 4; ++rt) {
            int a = rt * 16 + lm;
            int cs = (ks * 4 + lq) ^ lm;
            ah[rt] = *(const short8v*)(Ah + a * 128 + cs * 8);
            al[rt] = *(const short8v*)(Al + a * 128 + cs * 8);
        }
        #pragma unroll
        for (int ti = 0; ti < 4; ++ti) {
            int fid = ((w + ti * 4) * 4 + ks) * 64 + l;
            short8v bh = *(const short8v*)(Bh + (size_t)fid * 8);
            short8v bl = *(const short8v*)(Bl + (size_t)fid * 8);
            #pragma unroll
            for (int rt = 0; rt < 4; ++rt) {
                acc[rt][ti] = __builtin_amdgcn_mfma_f32_16x16x32_bf16(ah[rt], bh, acc[rt][ti], 0, 0, 0);
                acc[rt][ti] = __builtin_amdgcn_mfma_f32_16x16x32_bf16(al[rt], bh, acc[rt][ti], 0, 0, 0);
                acc[rt][ti] = __builtin_amdgcn_mfma_f32_16x16x32_bf16(ah[rt], bl, acc[rt][ti], 0, 0, 0);
            }
        }
    }

    float bvz[4], scv[4], shv[4];
    #pragma unroll
    for (int ti = 0; ti < 4; ++ti) {
        int c = (w + ti * 4) * 16 + lm;
        bvz[ti] = bias[c];
        float s = bg[c] * rsqrtf(bv[c] + BN_EPS);
        scv[ti] = s;
        shv[ti] = bb[c] - bm[c] * s;
    }

    const int q = tid >> 5, cg = tid & 31;
    const int sub = blockIdx.x * 8 + q;
    const size_t slotBase = (size_t)cumSeg[sub];
    const int fs = sM[q * 8];

    #pragma unroll
    for (int hf = 0; hf < 2; ++hf) {
        __syncthreads();
        #pragma unroll
        for (int tj = 0; tj < 2; ++tj) {
            int ti = 2 * hf + tj;
            int colh = (w + ti * 4) * 16 + lm - hf * 128;
            #pragma unroll
            for (int rt = 0; rt < 4; ++rt)
                #pragma unroll
                for (int r = 0; r < 4; ++r) {
                    int row = rt * 16 + lq * 4 + r;
                    float y = fast_tanh(acc[rt][ti][r] + bvz[ti]) * scv[ti] + shv[ti];
                    Yt[row * 132 + colh] = y;
                }
        }
        __syncthreads();

        float4 ys, ym;
        int cur = sM[q * 8];
        {
            float4 v = *(const float4*)(Yt + (q * 8) * 132 + cg * 4);
            ys = v; ym = v;
        }
        #pragma unroll
        for (int i = 1; i < 8; ++i) {
            float4 v = *(const float4*)(Yt + (q * 8 + i) * 132 + cg * 4);
            int m = sM[q * 8 + i];
            if (m == cur) {
                ys.x += v.x; ys.y += v.y; ys.z += v.z; ys.w += v.w;
                ym.x = fmaxf(ym.x, v.x); ym.y = fmaxf(ym.y, v.y);
                ym.z = fmaxf(ym.z, v.z); ym.w = fmaxf(ym.w, v.w);
            } else {
                float* p = partials + (slotBase + (cur - fs)) * 512 + hf * 128 + cg * 4;
                *(float4*)p         = ys;
                *(float4*)(p + 256) = ym;
                cur = m; ys = v; ym = v;
            }
        }
        float* p = partials + (slotBase + (cur - fs)) * 512 + hf * 128 + cg * 4;
        *(float4*)p         = ys;
        *(float4*)(p + 256) = ym;
    }
}

// ---------- combine partials -> final out (tanh fused) ----------

__global__ __launch_bounds__(256)
void k_combine(const float* __restrict__ partials,
               const int* __restrict__ binBase, const int* __restrict__ binCnt,
               const int* __restrict__ firstSeg, const int* __restrict__ cumSeg,
               float* __restrict__ Out)
{
    int sid = blockIdx.x * 4 + (threadIdx.x >> 6);
    if (sid >= 40000) return;
    int lane = threadIdx.x & 63;
    int b = binBase[sid], n = binCnt[sid];

    float4 s = make_float4(0.f, 0.f, 0.f, 0.f);
    float4 m = make_float4(-INFINITY, -INFINITY, -INFINITY, -INFINITY);
    if (n > 0) {
        int s0 = b >> 3, s1 = (b + n - 1) >> 3;
        for (int t = s0; t <= s1; ++t) {
            size_t slot = (size_t)cumSeg[t] + (sid - firstSeg[t]);
            const float4* P = (const float4*)(partials + slot * 512);
            float4 a = P[lane];
            float4 x = P[64 + lane];
            s.x += a.x; s.y += a.y; s.z += a.z; s.w += a.w;
            m.x = fmaxf(m.x, x.x); m.y = fmaxf(m.y, x.y);
            m.z = fmaxf(m.z, x.z); m.w = fmaxf(m.w, x.w);
        }
    }
    float4 os = make_float4(fast_tanh(s.x), fast_tanh(s.y), fast_tanh(s.z), fast_tanh(s.w));
    float4 om = make_float4(fast_tanh(m.x), fast_tanh(m.y), fast_tanh(m.z), fast_tanh(m.w));
    *(float4*)(Out + (size_t)sid * 512 + lane * 4)       = os;
    *(float4*)(Out + (size_t)sid * 512 + 256 + lane * 4) = om;
}

// ---------- launcher ----------

extern "C" void kernel_launch(void* const* d_in, const int* in_sizes, int n_in,
                              void* d_out, int out_size, void* d_ws, size_t ws_size,
                              hipStream_t stream)
{
    const float* atom = (const float*)d_in[0];
    const int*   memb = (const int*)d_in[1];
    const int*   adj1 = (const int*)d_in[2];
    const int*   adj2 = (const int*)d_in[3];
    const int*   adj3 = (const int*)d_in[4];
    const int*   adj4 = (const int*)d_in[5];
    const float* g1Ws = (const float*)d_in[6];
    const float* g1Wr = (const float*)d_in[7];
    const float* g1b  = (const float*)d_in[8];
    const float* g2Ws = (const float*)d_in[9];
    const float* g2Wr = (const float*)d_in[10];
    const float* g2b  = (const float*)d_in[11];
    const float* bn1g = (const float*)d_in[12];
    const float* bn1b = (const float*)d_in[13];
    const float* bn1m = (const float*)d_in[14];
    const float* bn1v = (const float*)d_in[15];
    const float* bn3g = (const float*)d_in[16];
    const float* bn3b = (const float*)d_in[17];
    const float* bn3m = (const float*)d_in[18];
    const float* bn3v = (const float*)d_in[19];
    const float* dW   = (const float*)d_in[20];
    const float* db   = (const float*)d_in[21];

    char* ws = (char*)d_ws;
    float* bufA = (float*)ws;                    // [1M][128] f32, 512 MB
    float* bufB = (float*)(ws + 512000000);      // [1M][128] f32, 512 MB
    float* out  = (float*)d_out;                 // [40000][512]

    // W fragments live in d_out (only combine writes d_out, at the very end):
    ushort_t* gFh  = (ushort_t*)out;             // gc2: 18432 frags x 16B
    ushort_t* gFl  = gFh + (size_t)18432 * 8;
    ushort_t* g1Fh = gFl + (size_t)18432 * 8;    // gc1: 13824 frags x 16B
    ushort_t* g1Fl = g1Fh + (size_t)13824 * 8;   // ends ~1.03 MB << 82 MB

    // scratch inside bufA (dead after pool2 reads it):
    int* perm     = (int*)bufA;                  // 1,000,000
    int* binCnt   = perm + 1000000;              // 40,000
    int* binBase  = binCnt + 40000;
    int* binFill  = binBase + 40000;
    int* firstSeg = binFill + 40000;             // 125,000
    int* segCnt   = firstSeg + 125000;
    int* cumSeg   = segCnt + 125000;             // ends < 6 MB
    ushort_t* dWh = (ushort_t*)(ws + 6200000);   // dense: 4096 frags x 16B
    ushort_t* dWl = (ushort_t*)(ws + 6400000);
    float* partials = (float*)(ws + 8000000);    // <=164,999 slots x 512 f32 = 338 MB

    // ---- W fragment prep (into d_out; read by gc kernels, overwritten by combine) ----
    k_prepW2<<<72, 256, 0, stream>>>(g2Ws, g2Wr, gFh, gFl);
    k_prepW1<<<54, 256, 0, stream>>>(g1Ws, g1Wr, g1Fh, g1Fl);

    // ---- gc1 (MFMA): atom -> bufA ----
    k_gc1m<0><<<(10000 + 63) / 64, 256, 0, stream>>>(atom, nullptr,
        g1Fh + (size_t)0 * 1536 * 8, g1Fl + (size_t)0 * 1536 * 8,
        nullptr, nullptr, g1b + 0 * 128,
        bn1g, bn1b, bn1m, bn1v, bufA, 0, 10000);
    k_gc1m<1><<<(240000 + 63) / 64, 256, 0, stream>>>(atom, adj1,
        g1Fh + (size_t)1 * 1536 * 8, g1Fl + (size_t)1 * 1536 * 8,
        g1Fh + (size_t)5 * 1536 * 8, g1Fl + (size_t)5 * 1536 * 8, g1b + 1 * 128,
        bn1g, bn1b, bn1m, bn1v, bufA, 10000, 240000);
    k_gc1m<2><<<(360000 + 63) / 64, 256, 0, stream>>>(atom, adj2,
        g1Fh + (size_t)2 * 1536 * 8, g1Fl + (size_t)2 * 1536 * 8,
        g1Fh + (size_t)6 * 1536 * 8, g1Fl + (size_t)6 * 1536 * 8, g1b + 2 * 128,
        bn1g, bn1b, bn1m, bn1v, bufA, 250000, 360000);
    k_gc1m<3><<<(250000 + 63) / 64, 256, 0, stream>>>(atom, adj3,
        g1Fh + (size_t)3 * 1536 * 8, g1Fl + (size_t)3 * 1536 * 8,
        g1Fh + (size_t)7 * 1536 * 8, g1Fl + (size_t)7 * 1536 * 8, g1b + 3 * 128,
        bn1g, bn1b, bn1m, bn1v, bufA, 610000, 250000);
    k_gc1m<4><<<(140000 + 63) / 64, 256, 0, stream>>>(atom, adj4,
        g1Fh + (size_t)4 * 1536 * 8, g1Fl + (size_t)4 * 1536 * 8,
        g1Fh + (size_t)8 * 1536 * 8, g1Fl + (size_t)8 * 1536 * 8, g1b + 4 * 128,
        bn1g, bn1b, bn1m, bn1v, bufA, 860000, 140000);

    // ---- pool1: bufA -> bufB ----
    k_pool<0><<<(10000 + 7) / 8, 256, 0, stream>>>(bufA, nullptr, bufB, 0, 10000);
    k_pool<1><<<(240000 + 7) / 8, 256, 0, stream>>>(bufA, adj1, bufB, 10000, 240000);
    k_pool<2><<<(360000 + 7) / 8, 256, 0, stream>>>(bufA, adj2, bufB, 250000, 360000);
    k_pool<3><<<(250000 + 7) / 8, 256, 0, stream>>>(bufA, adj3, bufB, 610000, 250000);
    k_pool<4><<<(140000 + 7) / 8, 256, 0, stream>>>(bufA, adj4, bufB, 860000, 140000);

    // ---- gc2 (MFMA): bufB -> bufA ----
    k_gc2m<0><<<(10000 + 63) / 64, 256, 0, stream>>>(bufB, nullptr,
        gFh + (size_t)0 * 2048 * 8, gFl + (size_t)0 * 2048 * 8,
        nullptr, nullptr, g2b + 0 * 128,
        bn1g, bn1b, bn1m, bn1v, bufA, 0, 10000);
    k_gc2m<1><<<(240000 + 63) / 64, 256, 0, stream>>>(bufB, adj1,
        gFh + (size_t)1 * 2048 * 8, gFl + (size_t)1 * 2048 * 8,
        gFh + (size_t)5 * 2048 * 8, gFl + (size_t)5 * 2048 * 8, g2b + 1 * 128,
        bn1g, bn1b, bn1m, bn1v, bufA, 10000, 240000);
    k_gc2m<2><<<(360000 + 63) / 64, 256, 0, stream>>>(bufB, adj2,
        gFh + (size_t)2 * 2048 * 8, gFl + (size_t)2 * 2048 * 8,
        gFh + (size_t)6 * 2048 * 8, gFl + (size_t)6 * 2048 * 8, g2b + 2 * 128,
        bn1g, bn1b, bn1m, bn1v, bufA, 250000, 360000);
    k_gc2m<3><<<(250000 + 63) / 64, 256, 0, stream>>>(bufB, adj3,
        gFh + (size_t)3 * 2048 * 8, gFl + (size_t)3 * 2048 * 8,
        gFh + (size_t)7 * 2048 * 8, gFl + (size_t)7 * 2048 * 8, g2b + 3 * 128,
        bn1g, bn1b, bn1m, bn1v, bufA, 610000, 250000);
    k_gc2m<4><<<(140000 + 63) / 64, 256, 0, stream>>>(bufB, adj4,
        gFh + (size_t)4 * 2048 * 8, gFl + (size_t)4 * 2048 * 8,
        gFh + (size_t)8 * 2048 * 8, gFl + (size_t)8 * 2048 * 8, g2b + 4 * 128,
        bn1g, bn1b, bn1m, bn1v, bufA, 860000, 140000);

    // ---- pool2: bufA -> bufB (dense input = bufB; bufA becomes scratch) ----
    k_pool<0><<<(10000 + 7) / 8, 256, 0, stream>>>(bufA, nullptr, bufB, 0, 10000);
    k_pool<1><<<(240000 + 7) / 8, 256, 0, stream>>>(bufA, adj1, bufB, 10000, 240000);
    k_pool<2><<<(360000 + 7) / 8, 256, 0, stream>>>(bufA, adj2, bufB, 250000, 360000);
    k_pool<3><<<(250000 + 7) / 8, 256, 0, stream>>>(bufA, adj3, bufB, 610000, 250000);
    k_pool<4><<<(140000 + 7) / 8, 256, 0, stream>>>(bufA, adj4, bufB, 860000, 140000);

    // ---- counting sort by membership + subtile meta + dense W frag prep ----
    k_zero_bins<<<(40000 + 255) / 256, 256, 0, stream>>>(binCnt, binFill);
    k_hist<<<(1000000 + 255) / 256, 256, 0, stream>>>(memb, binCnt);
    k_scan<<<1, 1024, 0, stream>>>(binCnt, binBase);
    k_scatter<<<(1000000 + 255) / 256, 256, 0, stream>>>(memb, binBase, binFill, perm);
    k_meta<<<(125000 + 255) / 256, 256, 0, stream>>>(memb, perm, firstSeg, segCnt);
    k_scan2<<<1, 1024, 0, stream>>>(segCnt, cumSeg);
    k_prepW<<<16, 256, 0, stream>>>(dW, dWh, dWl);

    // ---- dense via MFMA + tanh + bn3 -> subtile partials ----
    k_dense_mfma<<<15625, 256, 0, stream>>>(bufB, memb, perm, cumSeg, dWh, dWl,
        db, bn3g, bn3b, bn3m, bn3v, partials);

    // ---- combine partials -> out (fully overwrites d_out incl. frag regions) ----
    k_combine<<<10000, 256, 0, stream>>>(partials, binBase, binCnt,
        firstSeg, cumSeg, out);
}

// Round 9
// 3291.007 us; speedup vs baseline: 1.0512x; 1.0512x over previous
//
#include <hip/hip_runtime.h>
#include <hip/hip_bf16.h>
#include <cstdint>
#include <cstddef>

#define BN_EPS 1e-3f
typedef unsigned short ushort_t;
typedef unsigned int uint_t;
typedef __attribute__((ext_vector_type(8))) short short8v;   // 8 bf16 (4 VGPRs)
typedef __attribute__((ext_vector_type(4))) float f32x4;     // MFMA C/D

// ---------- numeric helpers ----------

__device__ __forceinline__ float fast_tanh(float x) {
    float xc = fminf(fmaxf(x, -12.0f), 12.0f);
    float e = __expf(2.0f * xc);
    return (e - 1.0f) / (e + 1.0f);
}

__device__ __forceinline__ float bf2f(uint_t u) {
    return __uint_as_float(u << 16);
}
__device__ __forceinline__ ushort_t f2bf(float f) {
    union { __hip_bfloat16 h; ushort_t u; } cv;
    cv.h = __float2bfloat16(f);   // RNE
    return cv.u;
}

// split 8 f32 -> 8 bf16 hi + 8 bf16 lo (lo = bf16(x - hi)), packed 16B each
__device__ __forceinline__ void split8(const float* f, uint4& h, uint4& lo) {
    uint_t hh[8], ll[8];
    #pragma unroll
    for (int j = 0; j < 8; ++j) {
        float x = f[j];
        ushort_t xh = f2bf(x);
        float xr = x - bf2f(xh);
        hh[j] = xh;
        ll[j] = f2bf(xr);
    }
    h  = make_uint4(hh[0] | (hh[1] << 16), hh[2] | (hh[3] << 16),
                    hh[4] | (hh[5] << 16), hh[6] | (hh[7] << 16));
    lo = make_uint4(ll[0] | (ll[1] << 16), ll[2] | (ll[3] << 16),
                    ll[4] | (ll[5] << 16), ll[6] | (ll[7] << 16));
}

// ---------- counting sort of atoms by membership (ascending) ----------

__global__ void k_zero_bins(int* __restrict__ binCnt, int* __restrict__ binFill) {
    int t = blockIdx.x * 256 + threadIdx.x;
    if (t < 40000) { binCnt[t] = 0; binFill[t] = 0; }
}

__global__ void k_hist(const int* __restrict__ memb, int* __restrict__ binCnt) {
    int t = blockIdx.x * 256 + threadIdx.x;
    if (t < 1000000) atomicAdd(&binCnt[memb[t]], 1);
}

__global__ __launch_bounds__(1024)
void k_scan(const int* __restrict__ binCnt, int* __restrict__ binBase) {
    __shared__ int part[1024];
    const int t = threadIdx.x;
    const int base = t * 40;
    int local[40];
    int s = 0;
    #pragma unroll
    for (int j = 0; j < 40; ++j) {
        int idx = base + j;
        int c = (idx < 40000) ? binCnt[idx] : 0;
        local[j] = s;
        s += c;
    }
    part[t] = s;
    __syncthreads();
    for (int off = 1; off < 1024; off <<= 1) {
        int v = (t >= off) ? part[t - off] : 0;
        __syncthreads();
        part[t] += v;
        __syncthreads();
    }
    int add = (t > 0) ? part[t - 1] : 0;
    #pragma unroll
    for (int j = 0; j < 40; ++j) {
        int idx = base + j;
        if (idx < 40000) binBase[idx] = add + local[j];
    }
}

__global__ void k_scatter(const int* __restrict__ memb, const int* __restrict__ binBase,
                          int* __restrict__ binFill, int* __restrict__ perm) {
    int t = blockIdx.x * 256 + threadIdx.x;
    if (t < 1000000) {
        int m = memb[t];
        int pos = binBase[m] + atomicAdd(&binFill[m], 1);
        perm[pos] = t;
    }
}

// ---------- subtile metadata: 125000 subtiles of 8 sorted rows ----------

__global__ void k_meta(const int* __restrict__ memb, const int* __restrict__ perm,
                       int* __restrict__ firstSeg, int* __restrict__ segCnt) {
    int t = blockIdx.x * 256 + threadIdx.x;
    if (t < 125000) {
        int f = memb[perm[8 * t]];
        int l = memb[perm[8 * t + 7]];
        firstSeg[t] = f;
        segCnt[t] = l - f + 1;
    }
}

__global__ __launch_bounds__(1024)
void k_scan2(const int* __restrict__ segCnt, int* __restrict__ cumSeg) {
    __shared__ int part[1024];
    const int t = threadIdx.x;
    const int base = t * 123;
    int s = 0;
    for (int j = 0; j < 123; ++j) {
        int idx = base + j;
        if (idx < 125000) s += segCnt[idx];
    }
    part[t] = s;
    __syncthreads();
    for (int off = 1; off < 1024; off <<= 1) {
        int v = (t >= off) ? part[t - off] : 0;
        __syncthreads();
        part[t] += v;
        __syncthreads();
    }
    int run = (t > 0) ? part[t - 1] : 0;
    for (int j = 0; j < 123; ++j) {
        int idx = base + j;
        if (idx < 125000) { cumSeg[idx] = run; run += segCnt[idx]; }
    }
}

// ---------- W fragment prep: dense [128][256] ----------
// fid = (tn*4 + ks)*64 + lane; lane j holds W[ks*32 + (lane>>4)*8 + j][tn*16 + (lane&15)]

__global__ void k_prepW(const float* __restrict__ W,
                        ushort_t* __restrict__ Bh, ushort_t* __restrict__ Bl) {
    int idx = blockIdx.x * 256 + threadIdx.x;
    if (idx >= 4096) return;
    int l = idx & 63, g = idx >> 6;       // g = tn*4 + ks
    int tn = g >> 2, ks = g & 3;
    int n = tn * 16 + (l & 15);
    int k0 = ks * 32 + (l >> 4) * 8;
    float f[8];
    #pragma unroll
    for (int j = 0; j < 8; ++j) f[j] = W[(size_t)(k0 + j) * 256 + n];
    uint4 h, lo; split8(f, h, lo);
    *(uint4*)(Bh + (size_t)idx * 8) = h;
    *(uint4*)(Bl + (size_t)idx * 8) = lo;
}

// ---------- W fragment prep: gc2's 9 matrices [128][128] (5 self + 4 rel) ----------

__global__ void k_prepW2(const float* __restrict__ Ws5, const float* __restrict__ Wr4,
                         ushort_t* __restrict__ Fh, ushort_t* __restrict__ Fl) {
    int idx = blockIdx.x * 256 + threadIdx.x;   // [0, 9*2048)
    if (idx >= 18432) return;
    int mat = idx >> 11;
    int fid = idx & 2047;
    int l = fid & 63, g = fid >> 6;
    int tn = g >> 2, ks = g & 3;
    int n = tn * 16 + (l & 15);
    int k0 = ks * 32 + (l >> 4) * 8;
    const float* W = (mat < 5) ? (Ws5 + (size_t)mat * 16384)
                               : (Wr4 + (size_t)(mat - 5) * 16384);
    float f[8];
    #pragma unroll
    for (int j = 0; j < 8; ++j) f[j] = W[(size_t)(k0 + j) * 128 + n];
    uint4 h, lo; split8(f, h, lo);
    *(uint4*)(Fh + (size_t)idx * 8) = h;
    *(uint4*)(Fl + (size_t)idx * 8) = lo;
}

// ---------- gc1 (+ tanh + bn1 fused), f32 VALU (K=75) — proven round-7 kernel ----------

template<int IN, int DEG>
__global__ __launch_bounds__(256, 2)
void k_gc(const float* __restrict__ X,     // full [1M][IN]
          const int*   __restrict__ adj,
          const float* __restrict__ Ws,    // [IN][128]
          const float* __restrict__ Wr,    // [IN][128]
          const float* __restrict__ bias,  // [128]
          const float* __restrict__ bg, const float* __restrict__ bb,
          const float* __restrict__ bm, const float* __restrict__ bv,
          float* __restrict__ Out,         // full [1M][128]
          int start, int count)
{
    __shared__ float sSelf[64 * IN];
    __shared__ float sNbr[64 * IN];

    const int tileBase = blockIdx.x * 64;

    for (int idx = threadIdx.x; idx < 64 * IN; idx += 256) {
        int a = idx / IN;
        int k = idx - a * IN;
        int ga = tileBase + a;
        float sv = 0.0f, nv = 0.0f;
        if (ga < count) {
            sv = X[(size_t)(start + ga) * IN + k];
            if constexpr (DEG > 0) {
                #pragma unroll
                for (int j = 0; j < DEG; ++j) {
                    int nb = adj[(size_t)ga * DEG + j];
                    nv += X[(size_t)nb * IN + k];
                }
            }
        }
        sSelf[a * IN + k] = sv;
        sNbr[a * IN + k]  = nv;
    }
    __syncthreads();

    const int as = threadIdx.x >> 4;        // 0..15
    const int c0 = (threadIdx.x & 15) * 8;

    float acc[4][8];
    #pragma unroll
    for (int i = 0; i < 4; ++i)
        #pragma unroll
        for (int u = 0; u < 8; ++u) acc[i][u] = 0.0f;

    #pragma unroll 4
    for (int k = 0; k < IN; ++k) {
        float wsv[8];
        *(float4*)(&wsv[0]) = *(const float4*)(Ws + (size_t)k * 128 + c0);
        *(float4*)(&wsv[4]) = *(const float4*)(Ws + (size_t)k * 128 + c0 + 4);
        float wrv[8];
        if constexpr (DEG > 0) {
            *(float4*)(&wrv[0]) = *(const float4*)(Wr + (size_t)k * 128 + c0);
            *(float4*)(&wrv[4]) = *(const float4*)(Wr + (size_t)k * 128 + c0 + 4);
        }
        #pragma unroll
        for (int i = 0; i < 4; ++i) {
            const int a = as + 16 * i;
            const float sv = sSelf[a * IN + k];
            #pragma unroll
            for (int u = 0; u < 8; ++u) acc[i][u] = fmaf(sv, wsv[u], acc[i][u]);
            if constexpr (DEG > 0) {
                const float nv = sNbr[a * IN + k];
                #pragma unroll
                for (int u = 0; u < 8; ++u) acc[i][u] = fmaf(nv, wrv[u], acc[i][u]);
            }
        }
    }

    float bvz[8], sc[8], sh[8];
    #pragma unroll
    for (int u = 0; u < 8; ++u) {
        int c = c0 + u;
        bvz[u] = bias[c];
        float s = bg[c] * rsqrtf(bv[c] + BN_EPS);
        sc[u] = s;
        sh[u] = bb[c] - bm[c] * s;
    }
    #pragma unroll
    for (int i = 0; i < 4; ++i) {
        int ga = tileBase + as + 16 * i;
        if (ga < count) {
            float o[8];
            #pragma unroll
            for (int u = 0; u < 8; ++u) {
                float t = fast_tanh(acc[i][u] + bvz[u]);
                o[u] = t * sc[u] + sh[u];
            }
            float* dst = Out + (size_t)(start + ga) * 128 + c0;
            *(float4*)dst       = *(float4*)(&o[0]);
            *(float4*)(dst + 4) = *(float4*)(&o[4]);
        }
    }
}

// ---------- gc2 via MFMA split-bf16 (tanh + bn1 fused) — proven round-7 kernel ----------

template<int DEG>
__global__ __launch_bounds__(256)
void k_gc2m(const float* __restrict__ X, const int* __restrict__ adj,
            const ushort_t* __restrict__ Wsh, const ushort_t* __restrict__ Wsl,
            const ushort_t* __restrict__ Wrh, const ushort_t* __restrict__ Wrl,
            const float* __restrict__ bias,
            const float* __restrict__ bg, const float* __restrict__ bb,
            const float* __restrict__ bm, const float* __restrict__ bv,
            float* __restrict__ Out, int start, int count)
{
    __shared__ __align__(16) ushort_t Sh[64 * 128];
    __shared__ __align__(16) ushort_t Sl[64 * 128];
    __shared__ __align__(16) ushort_t Nh[(DEG > 0) ? 64 * 128 : 8];
    __shared__ __align__(16) ushort_t Nl[(DEG > 0) ? 64 * 128 : 8];

    const int tid = threadIdx.x;
    const int tileBase = blockIdx.x * 64;

    for (int idx = tid; idx < 1024; idx += 256) {
        int a = idx >> 4, c = idx & 15;
        int ga = tileBase + a;
        float fs[8] = {0, 0, 0, 0, 0, 0, 0, 0};
        float fn[8] = {0, 0, 0, 0, 0, 0, 0, 0};
        if (ga < count) {
            const float* row = X + (size_t)(start + ga) * 128 + c * 8;
            *(float4*)(&fs[0]) = *(const float4*)row;
            *(float4*)(&fs[4]) = *(const float4*)(row + 4);
            if constexpr (DEG > 0) {
                #pragma unroll
                for (int j = 0; j < DEG; ++j) {
                    int nb = adj[(size_t)ga * DEG + j];
                    const float* nr = X + (size_t)nb * 128 + c * 8;
                    float4 q0 = *(const float4*)nr;
                    float4 q1 = *(const float4*)(nr + 4);
                    fn[0] += q0.x; fn[1] += q0.y; fn[2] += q0.z; fn[3] += q0.w;
                    fn[4] += q1.x; fn[5] += q1.y; fn[6] += q1.z; fn[7] += q1.w;
                }
            }
        }
        int cs = c ^ (a & 15);
        uint4 h, lo;
        split8(fs, h, lo);
        *(uint4*)(Sh + a * 128 + cs * 8) = h;
        *(uint4*)(Sl + a * 128 + cs * 8) = lo;
        if constexpr (DEG > 0) {
            split8(fn, h, lo);
            *(uint4*)(Nh + a * 128 + cs * 8) = h;
            *(uint4*)(Nl + a * 128 + cs * 8) = lo;
        }
    }
    __syncthreads();

    const int w = tid >> 6, l = tid & 63;
    const int lm = l & 15, lq = l >> 4;

    f32x4 acc[4][2];
    #pragma unroll
    for (int rt = 0; rt < 4; ++rt)
        #pragma unroll
        for (int ti = 0; ti < 2; ++ti)
            acc[rt][ti] = (f32x4){0.f, 0.f, 0.f, 0.f};

    for (int ks = 0; ks < 4; ++ks) {
        short8v ash[4], asl[4], anh[4], anl[4];
        #pragma unroll
        for (int rt = 0; rt < 4; ++rt) {
            int a = rt * 16 + lm;
            int cs = (ks * 4 + lq) ^ lm;
            ash[rt] = *(const short8v*)(Sh + a * 128 + cs * 8);
            asl[rt] = *(const short8v*)(Sl + a * 128 + cs * 8);
            if constexpr (DEG > 0) {
                anh[rt] = *(const short8v*)(Nh + a * 128 + cs * 8);
                anl[rt] = *(const short8v*)(Nl + a * 128 + cs * 8);
            }
        }
        #pragma unroll
        for (int ti = 0; ti < 2; ++ti) {
            int fid = ((w + ti * 4) * 4 + ks) * 64 + l;
            short8v bh = *(const short8v*)(Wsh + (size_t)fid * 8);
            short8v bl = *(const short8v*)(Wsl + (size_t)fid * 8);
            #pragma unroll
            for (int rt = 0; rt < 4; ++rt) {
                acc[rt][ti] = __builtin_amdgcn_mfma_f32_16x16x32_bf16(ash[rt], bh, acc[rt][ti], 0, 0, 0);
                acc[rt][ti] = __builtin_amdgcn_mfma_f32_16x16x32_bf16(asl[rt], bh, acc[rt][ti], 0, 0, 0);
                acc[rt][ti] = __builtin_amdgcn_mfma_f32_16x16x32_bf16(ash[rt], bl, acc[rt][ti], 0, 0, 0);
            }
            if constexpr (DEG > 0) {
                short8v rh = *(const short8v*)(Wrh + (size_t)fid * 8);
                short8v rl = *(const short8v*)(Wrl + (size_t)fid * 8);
                #pragma unroll
                for (int rt = 0; rt < 4; ++rt) {
                    acc[rt][ti] = __builtin_amdgcn_mfma_f32_16x16x32_bf16(anh[rt], rh, acc[rt][ti], 0, 0, 0);
                    acc[rt][ti] = __builtin_amdgcn_mfma_f32_16x16x32_bf16(anl[rt], rh, acc[rt][ti], 0, 0, 0);
                    acc[rt][ti] = __builtin_amdgcn_mfma_f32_16x16x32_bf16(anh[rt], rl, acc[rt][ti], 0, 0, 0);
                }
            }
        }
    }

    #pragma unroll
    for (int ti = 0; ti < 2; ++ti) {
        int cc = (w + ti * 4) * 16 + lm;
        float bz = bias[cc];
        float s = bg[cc] * rsqrtf(bv[cc] + BN_EPS);
        float sb = bb[cc] - bm[cc] * s;
        #pragma unroll
        for (int rt = 0; rt < 4; ++rt) {
            #pragma unroll
            for (int r = 0; r < 4; ++r) {
                int ga = tileBase + rt * 16 + lq * 4 + r;
                if (ga < count)
                    Out[(size_t)(start + ga) * 128 + cc] =
                        fast_tanh(acc[rt][ti][r] + bz) * s + sb;
            }
        }
    }
}

// ---------- graph pool (elementwise max over self + neighbors), f32 ----------

template<int DEG>
__global__ void k_pool(const float* __restrict__ X, const int* __restrict__ adj,
                       float* __restrict__ Out, int start, int count)
{
    int t = blockIdx.x * 256 + threadIdx.x;
    int a = t >> 5;
    if (a >= count) return;
    int c4 = t & 31;
    const float4* X4 = (const float4*)X;
    float4 v = X4[(size_t)(start + a) * 32 + c4];
    #pragma unroll
    for (int j = 0; j < DEG; ++j) {
        int nb = adj[(size_t)a * DEG + j];
        float4 q = X4[(size_t)nb * 32 + c4];
        v.x = fmaxf(v.x, q.x); v.y = fmaxf(v.y, q.y);
        v.z = fmaxf(v.z, q.z); v.w = fmaxf(v.w, q.w);
    }
    ((float4*)Out)[(size_t)(start + a) * 32 + c4] = v;
}

// ---------- dense via MFMA split-bf16 + FUSED pool2 (tanh + bn3) + subtile partials ----------
// Staging computes pooled row on the fly: pooled[p] = max(X[p], X[nbrs(p)]).
// Degree of p derived from static DEG_STARTS (atoms sorted by degree).

__global__ __launch_bounds__(256)
void k_dense_mfma(const float* __restrict__ X,      // [1M][128] = gc2 output
                  const int*   __restrict__ adj1, const int* __restrict__ adj2,
                  const int*   __restrict__ adj3, const int* __restrict__ adj4,
                  const int*   __restrict__ memb,
                  const int*   __restrict__ perm,    // membership-ascending
                  const int*   __restrict__ cumSeg,  // [125000]
                  const ushort_t* __restrict__ Bh,   // W frag hi [4096][8]
                  const ushort_t* __restrict__ Bl,   // W frag lo
                  const float* __restrict__ bias,    // [256]
                  const float* __restrict__ bg, const float* __restrict__ bb,
                  const float* __restrict__ bm, const float* __restrict__ bv,
                  float* __restrict__ partials)
{
    __shared__ __align__(16) char smem[33792];   // Ah[16KB]+Al[16KB] / Yt[64][132]f32
    __shared__ int sM[64];
    __shared__ int sP[64];
    ushort_t* Ah = (ushort_t*)smem;
    ushort_t* Al = (ushort_t*)(smem + 16384);
    float*    Yt = (float*)smem;

    const int tid = threadIdx.x;
    const int tileBase = blockIdx.x * 64;
    if (tid < 64) {
        int p = perm[tileBase + tid];
        sP[tid] = p;
        sM[tid] = memb[p];
    }
    __syncthreads();

    // stage pooled rows: pooled = max(self, nbrs), then split to bf16 hi/lo
    for (int idx = tid; idx < 1024; idx += 256) {
        int a = idx >> 4, c = idx & 15;
        int p = sP[a];
        const float* row = X + (size_t)p * 128 + c * 8;
        float f[8];
        *(float4*)(&f[0]) = *(const float4*)row;
        *(float4*)(&f[4]) = *(const float4*)(row + 4);

        int d, la;
        const int* adj;
        if (p < 250000) {
            if (p < 10000) { d = 0; adj = nullptr; la = 0; }
            else           { d = 1; adj = adj1; la = p - 10000; }
        } else if (p < 610000) { d = 2; adj = adj2; la = p - 250000; }
        else if (p < 860000)   { d = 3; adj = adj3; la = p - 610000; }
        else                   { d = 4; adj = adj4; la = p - 860000; }

        for (int j = 0; j < d; ++j) {
            int nb = adj[(size_t)la * d + j];
            const float* nr = X + (size_t)nb * 128 + c * 8;
            float4 q0 = *(const float4*)nr;
            float4 q1 = *(const float4*)(nr + 4);
            f[0] = fmaxf(f[0], q0.x); f[1] = fmaxf(f[1], q0.y);
            f[2] = fmaxf(f[2], q0.z); f[3] = fmaxf(f[3], q0.w);
            f[4] = fmaxf(f[4], q1.x); f[5] = fmaxf(f[5], q1.y);
            f[6] = fmaxf(f[6], q1.z); f[7] = fmaxf(f[7], q1.w);
        }

        uint4 h, lo; split8(f, h, lo);
        int cs = c ^ (a & 15);
        *(uint4*)(Ah + a * 128 + cs * 8) = h;
        *(uint4*)(Al + a * 128 + cs * 8) = lo;
    }
    __syncthreads();

    const int w = tid >> 6, l = tid & 63;
    const int lm = l & 15, lq = l >> 4;

    f32x4 acc[4][4];
    #pragma unroll
    for (int rt = 0; rt < 4; ++rt)
        #pragma unroll
        for (int ti = 0; ti < 4; ++ti)
            acc[rt][ti] = (f32x4){0.f, 0.f, 0.f, 0.f};

    for (int ks = 0; ks < 4; ++ks) {
        short8v ah[4], al[4];
        #pragma unroll
        for (int rt = 0; rt < 4; ++rt) {
            int a = rt * 16 + lm;
            int cs = (ks * 4 + lq) ^ lm;
            ah[rt] = *(const short8v*)(Ah + a * 128 + cs * 8);
            al[rt] = *(const short8v*)(Al + a * 128 + cs * 8);
        }
        #pragma unroll
        for (int ti = 0; ti < 4; ++ti) {
            int fid = ((w + ti * 4) * 4 + ks) * 64 + l;
            short8v bh = *(const short8v*)(Bh + (size_t)fid * 8);
            short8v bl = *(const short8v*)(Bl + (size_t)fid * 8);
            #pragma unroll
            for (int rt = 0; rt < 4; ++rt) {
                acc[rt][ti] = __builtin_amdgcn_mfma_f32_16x16x32_bf16(ah[rt], bh, acc[rt][ti], 0, 0, 0);
                acc[rt][ti] = __builtin_amdgcn_mfma_f32_16x16x32_bf16(al[rt], bh, acc[rt][ti], 0, 0, 0);
                acc[rt][ti] = __builtin_amdgcn_mfma_f32_16x16x32_bf16(ah[rt], bl, acc[rt][ti], 0, 0, 0);
            }
        }
    }

    float bvz[4], scv[4], shv[4];
    #pragma unroll
    for (int ti = 0; ti < 4; ++ti) {
        int c = (w + ti * 4) * 16 + lm;
        bvz[ti] = bias[c];
        float s = bg[c] * rsqrtf(bv[c] + BN_EPS);
        scv[ti] = s;
        shv[ti] = bb[c] - bm[c] * s;
    }

    const int q = tid >> 5, cg = tid & 31;
    const int sub = blockIdx.x * 8 + q;
    const size_t slotBase = (size_t)cumSeg[sub];
    const int fs = sM[q * 8];

    #pragma unroll
    for (int hf = 0; hf < 2; ++hf) {
        __syncthreads();
        #pragma unroll
        for (int tj = 0; tj < 2; ++tj) {
            int ti = 2 * hf + tj;
            int colh = (w + ti * 4) * 16 + lm - hf * 128;
            #pragma unroll
            for (int rt = 0; rt < 4; ++rt)
                #pragma unroll
                for (int r = 0; r < 4; ++r) {
                    int row = rt * 16 + lq * 4 + r;
                    float y = fast_tanh(acc[rt][ti][r] + bvz[ti]) * scv[ti] + shv[ti];
                    Yt[row * 132 + colh] = y;
                }
        }
        __syncthreads();

        float4 ys, ym;
        int cur = sM[q * 8];
        {
            float4 v = *(const float4*)(Yt + (q * 8) * 132 + cg * 4);
            ys = v; ym = v;
        }
        #pragma unroll
        for (int i = 1; i < 8; ++i) {
            float4 v = *(const float4*)(Yt + (q * 8 + i) * 132 + cg * 4);
            int m = sM[q * 8 + i];
            if (m == cur) {
                ys.x += v.x; ys.y += v.y; ys.z += v.z; ys.w += v.w;
                ym.x = fmaxf(ym.x, v.x); ym.y = fmaxf(ym.y, v.y);
                ym.z = fmaxf(ym.z, v.z); ym.w = fmaxf(ym.w, v.w);
            } else {
                float* pp = partials + (slotBase + (cur - fs)) * 512 + hf * 128 + cg * 4;
                *(float4*)pp         = ys;
                *(float4*)(pp + 256) = ym;
                cur = m; ys = v; ym = v;
            }
        }
        float* pp = partials + (slotBase + (cur - fs)) * 512 + hf * 128 + cg * 4;
        *(float4*)pp         = ys;
        *(float4*)(pp + 256) = ym;
    }
}

// ---------- combine partials -> final out (tanh fused) ----------

__global__ __launch_bounds__(256)
void k_combine(const float* __restrict__ partials,
               const int* __restrict__ binBase, const int* __restrict__ binCnt,
               const int* __restrict__ firstSeg, const int* __restrict__ cumSeg,
               float* __restrict__ Out)
{
    int sid = blockIdx.x * 4 + (threadIdx.x >> 6);
    if (sid >= 40000) return;
    int lane = threadIdx.x & 63;
    int b = binBase[sid], n = binCnt[sid];

    float4 s = make_float4(0.f, 0.f, 0.f, 0.f);
    float4 m = make_float4(-INFINITY, -INFINITY, -INFINITY, -INFINITY);
    if (n > 0) {
        int s0 = b >> 3, s1 = (b + n - 1) >> 3;
        for (int t = s0; t <= s1; ++t) {
            size_t slot = (size_t)cumSeg[t] + (sid - firstSeg[t]);
            const float4* P = (const float4*)(partials + slot * 512);
            float4 a = P[lane];
            float4 x = P[64 + lane];
            s.x += a.x; s.y += a.y; s.z += a.z; s.w += a.w;
            m.x = fmaxf(m.x, x.x); m.y = fmaxf(m.y, x.y);
            m.z = fmaxf(m.z, x.z); m.w = fmaxf(m.w, x.w);
        }
    }
    float4 os = make_float4(fast_tanh(s.x), fast_tanh(s.y), fast_tanh(s.z), fast_tanh(s.w));
    float4 om = make_float4(fast_tanh(m.x), fast_tanh(m.y), fast_tanh(m.z), fast_tanh(m.w));
    *(float4*)(Out + (size_t)sid * 512 + lane * 4)       = os;
    *(float4*)(Out + (size_t)sid * 512 + 256 + lane * 4) = om;
}

// ---------- launcher ----------

extern "C" void kernel_launch(void* const* d_in, const int* in_sizes, int n_in,
                              void* d_out, int out_size, void* d_ws, size_t ws_size,
                              hipStream_t stream)
{
    const float* atom = (const float*)d_in[0];
    const int*   memb = (const int*)d_in[1];
    const int*   adj1 = (const int*)d_in[2];
    const int*   adj2 = (const int*)d_in[3];
    const int*   adj3 = (const int*)d_in[4];
    const int*   adj4 = (const int*)d_in[5];
    const float* g1Ws = (const float*)d_in[6];
    const float* g1Wr = (const float*)d_in[7];
    const float* g1b  = (const float*)d_in[8];
    const float* g2Ws = (const float*)d_in[9];
    const float* g2Wr = (const float*)d_in[10];
    const float* g2b  = (const float*)d_in[11];
    const float* bn1g = (const float*)d_in[12];
    const float* bn1b = (const float*)d_in[13];
    const float* bn1m = (const float*)d_in[14];
    const float* bn1v = (const float*)d_in[15];
    const float* bn3g = (const float*)d_in[16];
    const float* bn3b = (const float*)d_in[17];
    const float* bn3m = (const float*)d_in[18];
    const float* bn3v = (const float*)d_in[19];
    const float* dW   = (const float*)d_in[20];
    const float* db   = (const float*)d_in[21];

    char* ws = (char*)d_ws;
    float* bufA = (float*)ws;                    // [1M][128] f32, 512 MB (gc1/gc2 out)
    float* bufB = (float*)(ws + 512000000);      // [1M][128] f32, 512 MB (pool1 out)
    float* out  = (float*)d_out;                 // [40000][512]

    // gc2 W fragments live in d_out (only combine writes d_out, at the very end):
    ushort_t* gFh = (ushort_t*)out;              // 18432 frags x 16B
    ushort_t* gFl = gFh + (size_t)18432 * 8;     // ends < 600 KB << 82 MB

    // scratch inside bufB (dead after gc2m reads it); bufA stays live for dense:
    char* sc = ws + 512000000;
    int* perm     = (int*)sc;                    // 1,000,000
    int* binCnt   = perm + 1000000;              // 40,000
    int* binBase  = binCnt + 40000;
    int* binFill  = binBase + 40000;
    int* firstSeg = binFill + 40000;             // 125,000
    int* segCnt   = firstSeg + 125000;
    int* cumSeg   = segCnt + 125000;             // ends < 6 MB into bufB
    ushort_t* dWh = (ushort_t*)(sc + 6200000);   // dense: 4096 frags x 16B
    ushort_t* dWl = (ushort_t*)(sc + 6400000);
    float* partials = (float*)(sc + 8000000);    // <=164,999 slots x 512 f32 = 338 MB

    // ---- gc2 W fragment prep (into d_out; read by gc2m, overwritten by combine) ----
    k_prepW2<<<72, 256, 0, stream>>>(g2Ws, g2Wr, gFh, gFl);

    // ---- gc1 (f32): atom -> bufA ----
    k_gc<75,0><<<(10000 + 63) / 64, 256, 0, stream>>>(atom, nullptr,
        g1Ws + (size_t)0 * 75 * 128, nullptr, g1b + 0 * 128,
        bn1g, bn1b, bn1m, bn1v, bufA, 0, 10000);
    k_gc<75,1><<<(240000 + 63) / 64, 256, 0, stream>>>(atom, adj1,
        g1Ws + (size_t)1 * 75 * 128, g1Wr + (size_t)0 * 75 * 128, g1b + 1 * 128,
        bn1g, bn1b, bn1m, bn1v, bufA, 10000, 240000);
    k_gc<75,2><<<(360000 + 63) / 64, 256, 0, stream>>>(atom, adj2,
        g1Ws + (size_t)2 * 75 * 128, g1Wr + (size_t)1 * 75 * 128, g1b + 2 * 128,
        bn1g, bn1b, bn1m, bn1v, bufA, 250000, 360000);
    k_gc<75,3><<<(250000 + 63) / 64, 256, 0, stream>>>(atom, adj3,
        g1Ws + (size_t)3 * 75 * 128, g1Wr + (size_t)2 * 75 * 128, g1b + 3 * 128,
        bn1g, bn1b, bn1m, bn1v, bufA, 610000, 250000);
    k_gc<75,4><<<(140000 + 63) / 64, 256, 0, stream>>>(atom, adj4,
        g1Ws + (size_t)4 * 75 * 128, g1Wr + (size_t)3 * 75 * 128, g1b + 4 * 128,
        bn1g, bn1b, bn1m, bn1v, bufA, 860000, 140000);

    // ---- pool1: bufA -> bufB ----
    k_pool<0><<<(10000 + 7) / 8, 256, 0, stream>>>(bufA, nullptr, bufB, 0, 10000);
    k_pool<1><<<(240000 + 7) / 8, 256, 0, stream>>>(bufA, adj1, bufB, 10000, 240000);
    k_pool<2><<<(360000 + 7) / 8, 256, 0, stream>>>(bufA, adj2, bufB, 250000, 360000);
    k_pool<3><<<(250000 + 7) / 8, 256, 0, stream>>>(bufA, adj3, bufB, 610000, 250000);
    k_pool<4><<<(140000 + 7) / 8, 256, 0, stream>>>(bufA, adj4, bufB, 860000, 140000);

    // ---- gc2 (MFMA): bufB -> bufA (bufB dead afterwards) ----
    k_gc2m<0><<<(10000 + 63) / 64, 256, 0, stream>>>(bufB, nullptr,
        gFh + (size_t)0 * 2048 * 8, gFl + (size_t)0 * 2048 * 8,
        nullptr, nullptr, g2b + 0 * 128,
        bn1g, bn1b, bn1m, bn1v, bufA, 0, 10000);
    k_gc2m<1><<<(240000 + 63) / 64, 256, 0, stream>>>(bufB, adj1,
        gFh + (size_t)1 * 2048 * 8, gFl + (size_t)1 * 2048 * 8,
        gFh + (size_t)5 * 2048 * 8, gFl + (size_t)5 * 2048 * 8, g2b + 1 * 128,
        bn1g, bn1b, bn1m, bn1v, bufA, 10000, 240000);
    k_gc2m<2><<<(360000 + 63) / 64, 256, 0, stream>>>(bufB, adj2,
        gFh + (size_t)2 * 2048 * 8, gFl + (size_t)2 * 2048 * 8,
        gFh + (size_t)6 * 2048 * 8, gFl + (size_t)6 * 2048 * 8, g2b + 2 * 128,
        bn1g, bn1b, bn1m, bn1v, bufA, 250000, 360000);
    k_gc2m<3><<<(250000 + 63) / 64, 256, 0, stream>>>(bufB, adj3,
        gFh + (size_t)3 * 2048 * 8, gFl + (size_t)3 * 2048 * 8,
        gFh + (size_t)7 * 2048 * 8, gFl + (size_t)7 * 2048 * 8, g2b + 3 * 128,
        bn1g, bn1b, bn1m, bn1v, bufA, 610000, 250000);
    k_gc2m<4><<<(140000 + 63) / 64, 256, 0, stream>>>(bufB, adj4,
        gFh + (size_t)4 * 2048 * 8, gFl + (size_t)4 * 2048 * 8,
        gFh + (size_t)8 * 2048 * 8, gFl + (size_t)8 * 2048 * 8, g2b + 4 * 128,
        bn1g, bn1b, bn1m, bn1v, bufA, 860000, 140000);

    // ---- counting sort + subtile meta + dense W frag prep (scratch in bufB) ----
    k_zero_bins<<<(40000 + 255) / 256, 256, 0, stream>>>(binCnt, binFill);
    k_hist<<<(1000000 + 255) / 256, 256, 0, stream>>>(memb, binCnt);
    k_scan<<<1, 1024, 0, stream>>>(binCnt, binBase);
    k_scatter<<<(1000000 + 255) / 256, 256, 0, stream>>>(memb, binBase, binFill, perm);
    k_meta<<<(125000 + 255) / 256, 256, 0, stream>>>(memb, perm, firstSeg, segCnt);
    k_scan2<<<1, 1024, 0, stream>>>(segCnt, cumSeg);
    k_prepW<<<16, 256, 0, stream>>>(dW, dWh, dWl);

    // ---- dense (MFMA, fused pool2) : bufA -> subtile partials ----
    k_dense_mfma<<<15625, 256, 0, stream>>>(bufA, adj1, adj2, adj3, adj4,
        memb, perm, cumSeg, dWh, dWl,
        db, bn3g, bn3b, bn3m, bn3v, partials);

    // ---- combine partials -> out (fully overwrites d_out incl. frag region) ----
    k_combine<<<10000, 256, 0, stream>>>(partials, binBase, binCnt,
        firstSeg, cumSeg, out);
}

// Round 10
// 3227.683 us; speedup vs baseline: 1.0718x; 1.0196x over previous
//
#include <hip/hip_runtime.h>
#include <hip/hip_bf16.h>
#include <cstdint>
#include <cstddef>

#define BN_EPS 1e-3f
typedef unsigned short ushort_t;
typedef unsigned int uint_t;
typedef __attribute__((ext_vector_type(8))) short short8v;   // 8 bf16 (4 VGPRs)
typedef __attribute__((ext_vector_type(4))) float f32x4;     // MFMA C/D

// ---------- numeric helpers ----------

__device__ __forceinline__ float fast_tanh(float x) {
    float xc = fminf(fmaxf(x, -12.0f), 12.0f);
    float e = __expf(2.0f * xc);
    return (e - 1.0f) / (e + 1.0f);
}

__device__ __forceinline__ float bf2f(uint_t u) {
    return __uint_as_float(u << 16);
}
__device__ __forceinline__ ushort_t f2bf(float f) {
    union { __hip_bfloat16 h; ushort_t u; } cv;
    cv.h = __float2bfloat16(f);   // RNE
    return cv.u;
}

// split 8 f32 -> 8 bf16 hi + 8 bf16 lo (lo = bf16(x - hi)), packed 16B each
__device__ __forceinline__ void split8(const float* f, uint4& h, uint4& lo) {
    uint_t hh[8], ll[8];
    #pragma unroll
    for (int j = 0; j < 8; ++j) {
        float x = f[j];
        ushort_t xh = f2bf(x);
        float xr = x - bf2f(xh);
        hh[j] = xh;
        ll[j] = f2bf(xr);
    }
    h  = make_uint4(hh[0] | (hh[1] << 16), hh[2] | (hh[3] << 16),
                    hh[4] | (hh[5] << 16), hh[6] | (hh[7] << 16));
    lo = make_uint4(ll[0] | (ll[1] << 16), ll[2] | (ll[3] << 16),
                    ll[4] | (ll[5] << 16), ll[6] | (ll[7] << 16));
}

// ---------- counting sort of atoms by membership (ascending) ----------

__global__ void k_zero_bins(int* __restrict__ binCnt, int* __restrict__ binFill) {
    int t = blockIdx.x * 256 + threadIdx.x;
    if (t < 40000) { binCnt[t] = 0; binFill[t] = 0; }
}

__global__ void k_hist(const int* __restrict__ memb, int* __restrict__ binCnt) {
    int t = blockIdx.x * 256 + threadIdx.x;
    if (t < 1000000) atomicAdd(&binCnt[memb[t]], 1);
}

__global__ __launch_bounds__(1024)
void k_scan(const int* __restrict__ binCnt, int* __restrict__ binBase) {
    __shared__ int part[1024];
    const int t = threadIdx.x;
    const int base = t * 40;
    int local[40];
    int s = 0;
    #pragma unroll
    for (int j = 0; j < 40; ++j) {
        int idx = base + j;
        int c = (idx < 40000) ? binCnt[idx] : 0;
        local[j] = s;
        s += c;
    }
    part[t] = s;
    __syncthreads();
    for (int off = 1; off < 1024; off <<= 1) {
        int v = (t >= off) ? part[t - off] : 0;
        __syncthreads();
        part[t] += v;
        __syncthreads();
    }
    int add = (t > 0) ? part[t - 1] : 0;
    #pragma unroll
    for (int j = 0; j < 40; ++j) {
        int idx = base + j;
        if (idx < 40000) binBase[idx] = add + local[j];
    }
}

__global__ void k_scatter(const int* __restrict__ memb, const int* __restrict__ binBase,
                          int* __restrict__ binFill, int* __restrict__ perm) {
    int t = blockIdx.x * 256 + threadIdx.x;
    if (t < 1000000) {
        int m = memb[t];
        int pos = binBase[m] + atomicAdd(&binFill[m], 1);
        perm[pos] = t;
    }
}

// ---------- subtile metadata: 125000 subtiles of 8 sorted rows ----------

__global__ void k_meta(const int* __restrict__ memb, const int* __restrict__ perm,
                       int* __restrict__ firstSeg, int* __restrict__ segCnt) {
    int t = blockIdx.x * 256 + threadIdx.x;
    if (t < 125000) {
        int f = memb[perm[8 * t]];
        int l = memb[perm[8 * t + 7]];
        firstSeg[t] = f;
        segCnt[t] = l - f + 1;
    }
}

__global__ __launch_bounds__(1024)
void k_scan2(const int* __restrict__ segCnt, int* __restrict__ cumSeg) {
    __shared__ int part[1024];
    const int t = threadIdx.x;
    const int base = t * 123;
    int s = 0;
    for (int j = 0; j < 123; ++j) {
        int idx = base + j;
        if (idx < 125000) s += segCnt[idx];
    }
    part[t] = s;
    __syncthreads();
    for (int off = 1; off < 1024; off <<= 1) {
        int v = (t >= off) ? part[t - off] : 0;
        __syncthreads();
        part[t] += v;
        __syncthreads();
    }
    int run = (t > 0) ? part[t - 1] : 0;
    for (int j = 0; j < 123; ++j) {
        int idx = base + j;
        if (idx < 125000) { cumSeg[idx] = run; run += segCnt[idx]; }
    }
}

// ---------- W fragment prep: dense [128][256] ----------
// fid = (tn*4 + ks)*64 + lane; lane j holds W[ks*32 + (lane>>4)*8 + j][tn*16 + (lane&15)]

__global__ void k_prepW(const float* __restrict__ W,
                        ushort_t* __restrict__ Bh, ushort_t* __restrict__ Bl) {
    int idx = blockIdx.x * 256 + threadIdx.x;
    if (idx >= 4096) return;
    int l = idx & 63, g = idx >> 6;       // g = tn*4 + ks
    int tn = g >> 2, ks = g & 3;
    int n = tn * 16 + (l & 15);
    int k0 = ks * 32 + (l >> 4) * 8;
    float f[8];
    #pragma unroll
    for (int j = 0; j < 8; ++j) f[j] = W[(size_t)(k0 + j) * 256 + n];
    uint4 h, lo; split8(f, h, lo);
    *(uint4*)(Bh + (size_t)idx * 8) = h;
    *(uint4*)(Bl + (size_t)idx * 8) = lo;
}

// ---------- W fragment prep: gc2's 9 matrices [128][128] (5 self + 4 rel) ----------

__global__ void k_prepW2(const float* __restrict__ Ws5, const float* __restrict__ Wr4,
                         ushort_t* __restrict__ Fh, ushort_t* __restrict__ Fl) {
    int idx = blockIdx.x * 256 + threadIdx.x;   // [0, 9*2048)
    if (idx >= 18432) return;
    int mat = idx >> 11;
    int fid = idx & 2047;
    int l = fid & 63, g = fid >> 6;
    int tn = g >> 2, ks = g & 3;
    int n = tn * 16 + (l & 15);
    int k0 = ks * 32 + (l >> 4) * 8;
    const float* W = (mat < 5) ? (Ws5 + (size_t)mat * 16384)
                               : (Wr4 + (size_t)(mat - 5) * 16384);
    float f[8];
    #pragma unroll
    for (int j = 0; j < 8; ++j) f[j] = W[(size_t)(k0 + j) * 128 + n];
    uint4 h, lo; split8(f, h, lo);
    *(uint4*)(Fh + (size_t)idx * 8) = h;
    *(uint4*)(Fl + (size_t)idx * 8) = lo;
}

// ---------- W fragment prep: gc1's 9 matrices [75][128], K padded to 96 ----------
// per matrix: 1536 frags (tn 0..7, ks 0..2, lane 0..63); k >= 75 -> 0.

__global__ void k_prepW1(const float* __restrict__ Ws5, const float* __restrict__ Wr4,
                         ushort_t* __restrict__ Fh, ushort_t* __restrict__ Fl) {
    int idx = blockIdx.x * 256 + threadIdx.x;   // [0, 9*1536)
    if (idx >= 13824) return;
    int mat = idx / 1536;
    int fid = idx - mat * 1536;
    int l = fid & 63, g = fid >> 6;             // g = tn*3 + ks
    int tn = g / 3, ks = g - tn * 3;
    int n = tn * 16 + (l & 15);
    int k0 = ks * 32 + (l >> 4) * 8;
    const float* W = (mat < 5) ? (Ws5 + (size_t)mat * 9600)
                               : (Wr4 + (size_t)(mat - 5) * 9600);
    float f[8];
    #pragma unroll
    for (int j = 0; j < 8; ++j)
        f[j] = (k0 + j < 75) ? W[(size_t)(k0 + j) * 128 + n] : 0.0f;
    uint4 h, lo; split8(f, h, lo);
    *(uint4*)(Fh + (size_t)idx * 8) = h;
    *(uint4*)(Fl + (size_t)idx * 8) = lo;
}

// ---------- gc1 via MFMA split-bf16 (tanh + bn1 fused), K=75 padded to 96 ----------
// v2: chunk-vectorized staging — thread owns (row, 8-k chunk): 8 predicated
// scalar loads per operand, one split8, b128 LDS writes (8x fewer LDS ops
// than round-8's scalar staging).

template<int DEG>
__global__ __launch_bounds__(256)
void k_gc1m(const float* __restrict__ X, const int* __restrict__ adj,
            const ushort_t* __restrict__ Wsh, const ushort_t* __restrict__ Wsl,
            const ushort_t* __restrict__ Wrh, const ushort_t* __restrict__ Wrl,
            const float* __restrict__ bias,
            const float* __restrict__ bg, const float* __restrict__ bb,
            const float* __restrict__ bm, const float* __restrict__ bv,
            float* __restrict__ Out, int start, int count)
{
    __shared__ __align__(16) ushort_t Sh[64 * 128];
    __shared__ __align__(16) ushort_t Sl[64 * 128];
    __shared__ __align__(16) ushort_t Nh[(DEG > 0) ? 64 * 128 : 8];
    __shared__ __align__(16) ushort_t Nl[(DEG > 0) ? 64 * 128 : 8];

    const int tid = threadIdx.x;
    const int tileBase = blockIdx.x * 64;

    // stage 12 chunks x 8 k per row (covers k=0..95; zeros pad k>=75)
    for (int idx = tid; idx < 64 * 12; idx += 256) {
        int a = idx / 12;
        int c = idx - a * 12;
        int k0 = c * 8;
        int ga = tileBase + a;
        float fs[8] = {0, 0, 0, 0, 0, 0, 0, 0};
        float fn[8] = {0, 0, 0, 0, 0, 0, 0, 0};
        if (ga < count) {
            const float* row = X + (size_t)(start + ga) * 75;
            #pragma unroll
            for (int j = 0; j < 8; ++j) {
                int k = k0 + j;
                if (k < 75) fs[j] = row[k];
            }
            if constexpr (DEG > 0) {
                #pragma unroll
                for (int jj = 0; jj < DEG; ++jj) {
                    int nb = adj[(size_t)ga * DEG + jj];
                    const float* nr = X + (size_t)nb * 75;
                    #pragma unroll
                    for (int j = 0; j < 8; ++j) {
                        int k = k0 + j;
                        if (k < 75) fn[j] += nr[k];
                    }
                }
            }
        }
        int cs = c ^ (a & 15);
        uint4 h, lo;
        split8(fs, h, lo);
        *(uint4*)(Sh + a * 128 + cs * 8) = h;
        *(uint4*)(Sl + a * 128 + cs * 8) = lo;
        if constexpr (DEG > 0) {
            split8(fn, h, lo);
            *(uint4*)(Nh + a * 128 + cs * 8) = h;
            *(uint4*)(Nl + a * 128 + cs * 8) = lo;
        }
    }
    __syncthreads();

    const int w = tid >> 6, l = tid & 63;
    const int lm = l & 15, lq = l >> 4;

    f32x4 acc[4][2];
    #pragma unroll
    for (int rt = 0; rt < 4; ++rt)
        #pragma unroll
        for (int ti = 0; ti < 2; ++ti)
            acc[rt][ti] = (f32x4){0.f, 0.f, 0.f, 0.f};

    for (int ks = 0; ks < 3; ++ks) {
        short8v ash[4], asl[4], anh[4], anl[4];
        #pragma unroll
        for (int rt = 0; rt < 4; ++rt) {
            int a = rt * 16 + lm;
            int cs = (ks * 4 + lq) ^ lm;
            ash[rt] = *(const short8v*)(Sh + a * 128 + cs * 8);
            asl[rt] = *(const short8v*)(Sl + a * 128 + cs * 8);
            if constexpr (DEG > 0) {
                anh[rt] = *(const short8v*)(Nh + a * 128 + cs * 8);
                anl[rt] = *(const short8v*)(Nl + a * 128 + cs * 8);
            }
        }
        #pragma unroll
        for (int ti = 0; ti < 2; ++ti) {
            int fid = ((w + ti * 4) * 3 + ks) * 64 + l;
            short8v bh = *(const short8v*)(Wsh + (size_t)fid * 8);
            short8v bl = *(const short8v*)(Wsl + (size_t)fid * 8);
            #pragma unroll
            for (int rt = 0; rt < 4; ++rt) {
                acc[rt][ti] = __builtin_amdgcn_mfma_f32_16x16x32_bf16(ash[rt], bh, acc[rt][ti], 0, 0, 0);
                acc[rt][ti] = __builtin_amdgcn_mfma_f32_16x16x32_bf16(asl[rt], bh, acc[rt][ti], 0, 0, 0);
                acc[rt][ti] = __builtin_amdgcn_mfma_f32_16x16x32_bf16(ash[rt], bl, acc[rt][ti], 0, 0, 0);
            }
            if constexpr (DEG > 0) {
                short8v rh = *(const short8v*)(Wrh + (size_t)fid * 8);
                short8v rl = *(const short8v*)(Wrl + (size_t)fid * 8);
                #pragma unroll
                for (int rt = 0; rt < 4; ++rt) {
                    acc[rt][ti] = __builtin_amdgcn_mfma_f32_16x16x32_bf16(anh[rt], rh, acc[rt][ti], 0, 0, 0);
                    acc[rt][ti] = __builtin_amdgcn_mfma_f32_16x16x32_bf16(anl[rt], rh, acc[rt][ti], 0, 0, 0);
                    acc[rt][ti] = __builtin_amdgcn_mfma_f32_16x16x32_bf16(anh[rt], rl, acc[rt][ti], 0, 0, 0);
                }
            }
        }
    }

    // epilogue: +bias, tanh, bn1; direct stores (C/D: col=lm, row=lq*4+r)
    #pragma unroll
    for (int ti = 0; ti < 2; ++ti) {
        int cc = (w + ti * 4) * 16 + lm;
        float bz = bias[cc];
        float s = bg[cc] * rsqrtf(bv[cc] + BN_EPS);
        float sb = bb[cc] - bm[cc] * s;
        #pragma unroll
        for (int rt = 0; rt < 4; ++rt) {
            #pragma unroll
            for (int r = 0; r < 4; ++r) {
                int ga = tileBase + rt * 16 + lq * 4 + r;
                if (ga < count)
                    Out[(size_t)(start + ga) * 128 + cc] =
                        fast_tanh(acc[rt][ti][r] + bz) * s + sb;
            }
        }
    }
}

// ---------- gc2 via MFMA split-bf16 (tanh + bn1 fused) — proven round-7 kernel ----------

template<int DEG>
__global__ __launch_bounds__(256)
void k_gc2m(const float* __restrict__ X, const int* __restrict__ adj,
            const ushort_t* __restrict__ Wsh, const ushort_t* __restrict__ Wsl,
            const ushort_t* __restrict__ Wrh, const ushort_t* __restrict__ Wrl,
            const float* __restrict__ bias,
            const float* __restrict__ bg, const float* __restrict__ bb,
            const float* __restrict__ bm, const float* __restrict__ bv,
            float* __restrict__ Out, int start, int count)
{
    __shared__ __align__(16) ushort_t Sh[64 * 128];
    __shared__ __align__(16) ushort_t Sl[64 * 128];
    __shared__ __align__(16) ushort_t Nh[(DEG > 0) ? 64 * 128 : 8];
    __shared__ __align__(16) ushort_t Nl[(DEG > 0) ? 64 * 128 : 8];

    const int tid = threadIdx.x;
    const int tileBase = blockIdx.x * 64;

    for (int idx = tid; idx < 1024; idx += 256) {
        int a = idx >> 4, c = idx & 15;
        int ga = tileBase + a;
        float fs[8] = {0, 0, 0, 0, 0, 0, 0, 0};
        float fn[8] = {0, 0, 0, 0, 0, 0, 0, 0};
        if (ga < count) {
            const float* row = X + (size_t)(start + ga) * 128 + c * 8;
            *(float4*)(&fs[0]) = *(const float4*)row;
            *(float4*)(&fs[4]) = *(const float4*)(row + 4);
            if constexpr (DEG > 0) {
                #pragma unroll
                for (int j = 0; j < DEG; ++j) {
                    int nb = adj[(size_t)ga * DEG + j];
                    const float* nr = X + (size_t)nb * 128 + c * 8;
                    float4 q0 = *(const float4*)nr;
                    float4 q1 = *(const float4*)(nr + 4);
                    fn[0] += q0.x; fn[1] += q0.y; fn[2] += q0.z; fn[3] += q0.w;
                    fn[4] += q1.x; fn[5] += q1.y; fn[6] += q1.z; fn[7] += q1.w;
                }
            }
        }
        int cs = c ^ (a & 15);
        uint4 h, lo;
        split8(fs, h, lo);
        *(uint4*)(Sh + a * 128 + cs * 8) = h;
        *(uint4*)(Sl + a * 128 + cs * 8) = lo;
        if constexpr (DEG > 0) {
            split8(fn, h, lo);
            *(uint4*)(Nh + a * 128 + cs * 8) = h;
            *(uint4*)(Nl + a * 128 + cs * 8) = lo;
        }
    }
    __syncthreads();

    const int w = tid >> 6, l = tid & 63;
    const int lm = l & 15, lq = l >> 4;

    f32x4 acc[4][2];
    #pragma unroll
    for (int rt = 0; rt < 4; ++rt)
        #pragma unroll
        for (int ti = 0; ti < 2; ++ti)
            acc[rt][ti] = (f32x4){0.f, 0.f, 0.f, 0.f};

    for (int ks = 0; ks < 4; ++ks) {
        short8v ash[4], asl[4], anh[4], anl[4];
        #pragma unroll
        for (int rt = 0; rt < 4; ++rt) {
            int a = rt * 16 + lm;
            int cs = (ks * 4 + lq) ^ lm;
            ash[rt] = *(const short8v*)(Sh + a * 128 + cs * 8);
            asl[rt] = *(const short8v*)(Sl + a * 128 + cs * 8);
            if constexpr (DEG > 0) {
                anh[rt] = *(const short8v*)(Nh + a * 128 + cs * 8);
                anl[rt] = *(const short8v*)(Nl + a * 128 + cs * 8);
            }
        }
        #pragma unroll
        for (int ti = 0; ti < 2; ++ti) {
            int fid = ((w + ti * 4) * 4 + ks) * 64 + l;
            short8v bh = *(const short8v*)(Wsh + (size_t)fid * 8);
            short8v bl = *(const short8v*)(Wsl + (size_t)fid * 8);
            #pragma unroll
            for (int rt = 0; rt < 4; ++rt) {
                acc[rt][ti] = __builtin_amdgcn_mfma_f32_16x16x32_bf16(ash[rt], bh, acc[rt][ti], 0, 0, 0);
                acc[rt][ti] = __builtin_amdgcn_mfma_f32_16x16x32_bf16(asl[rt], bh, acc[rt][ti], 0, 0, 0);
                acc[rt][ti] = __builtin_amdgcn_mfma_f32_16x16x32_bf16(ash[rt], bl, acc[rt][ti], 0, 0, 0);
            }
            if constexpr (DEG > 0) {
                short8v rh = *(const short8v*)(Wrh + (size_t)fid * 8);
                short8v rl = *(const short8v*)(Wrl + (size_t)fid * 8);
                #pragma unroll
                for (int rt = 0; rt < 4; ++rt) {
                    acc[rt][ti] = __builtin_amdgcn_mfma_f32_16x16x32_bf16(anh[rt], rh, acc[rt][ti], 0, 0, 0);
                    acc[rt][ti] = __builtin_amdgcn_mfma_f32_16x16x32_bf16(anl[rt], rh, acc[rt][ti], 0, 0, 0);
                    acc[rt][ti] = __builtin_amdgcn_mfma_f32_16x16x32_bf16(anh[rt], rl, acc[rt][ti], 0, 0, 0);
                }
            }
        }
    }

    #pragma unroll
    for (int ti = 0; ti < 2; ++ti) {
        int cc = (w + ti * 4) * 16 + lm;
        float bz = bias[cc];
        float s = bg[cc] * rsqrtf(bv[cc] + BN_EPS);
        float sb = bb[cc] - bm[cc] * s;
        #pragma unroll
        for (int rt = 0; rt < 4; ++rt) {
            #pragma unroll
            for (int r = 0; r < 4; ++r) {
                int ga = tileBase + rt * 16 + lq * 4 + r;
                if (ga < count)
                    Out[(size_t)(start + ga) * 128 + cc] =
                        fast_tanh(acc[rt][ti][r] + bz) * s + sb;
            }
        }
    }
}

// ---------- graph pool (elementwise max over self + neighbors), f32 ----------

template<int DEG>
__global__ void k_pool(const float* __restrict__ X, const int* __restrict__ adj,
                       float* __restrict__ Out, int start, int count)
{
    int t = blockIdx.x * 256 + threadIdx.x;
    int a = t >> 5;
    if (a >= count) return;
    int c4 = t & 31;
    const float4* X4 = (const float4*)X;
    float4 v = X4[(size_t)(start + a) * 32 + c4];
    #pragma unroll
    for (int j = 0; j < DEG; ++j) {
        int nb = adj[(size_t)a * DEG + j];
        float4 q = X4[(size_t)nb * 32 + c4];
        v.x = fmaxf(v.x, q.x); v.y = fmaxf(v.y, q.y);
        v.z = fmaxf(v.z, q.z); v.w = fmaxf(v.w, q.w);
    }
    ((float4*)Out)[(size_t)(start + a) * 32 + c4] = v;
}

// ---------- dense via MFMA split-bf16 (tanh + bn3) + subtile partials ----------

__global__ __launch_bounds__(256)
void k_dense_mfma(const float* __restrict__ X,      // [1M][128] (pool2 out)
                  const int*   __restrict__ memb,
                  const int*   __restrict__ perm,    // membership-ascending
                  const int*   __restrict__ cumSeg,  // [125000]
                  const ushort_t* __restrict__ Bh,   // W frag hi [4096][8]
                  const ushort_t* __restrict__ Bl,   // W frag lo
                  const float* __restrict__ bias,    // [256]
                  const float* __restrict__ bg, const float* __restrict__ bb,
                  const float* __restrict__ bm, const float* __restrict__ bv,
                  float* __restrict__ partials)
{
    __shared__ __align__(16) char smem[33792];   // Ah[16KB]+Al[16KB] / Yt[64][132]f32
    __shared__ int sM[64];
    __shared__ int sP[64];
    ushort_t* Ah = (ushort_t*)smem;
    ushort_t* Al = (ushort_t*)(smem + 16384);
    float*    Yt = (float*)smem;

    const int tid = threadIdx.x;
    const int tileBase = blockIdx.x * 64;
    if (tid < 64) {
        int p = perm[tileBase + tid];
        sP[tid] = p;
        sM[tid] = memb[p];
    }
    __syncthreads();

    for (int idx = tid; idx < 1024; idx += 256) {
        int a = idx >> 4, c = idx & 15;
        const float* row = X + (size_t)sP[a] * 128 + c * 8;
        float f[8];
        *(float4*)(&f[0]) = *(const float4*)row;
        *(float4*)(&f[4]) = *(const float4*)(row + 4);
        uint4 h, lo; split8(f, h, lo);
        int cs = c ^ (a & 15);
        *(uint4*)(Ah + a * 128 + cs * 8) = h;
        *(uint4*)(Al + a * 128 + cs * 8) = lo;
    }
    __syncthreads();

    const int w = tid >> 6, l = tid & 63;
    const int lm = l & 15, lq = l >> 4;

    f32x4 acc[4][4];
    #pragma unroll
    for (int rt = 0; rt < 4; ++rt)
        #pragma unroll
        for (int ti = 0; ti < 4; ++ti)
            acc[rt][ti] = (f32x4){0.f, 0.f, 0.f, 0.f};

    for (int ks = 0; ks < 4; ++ks) {
        short8v ah[4], al[4];
        #pragma unroll
        for (int rt = 0; rt < 4; ++rt) {
            int a = rt * 16 + lm;
            int cs = (ks * 4 + lq) ^ lm;
            ah[rt] = *(const short8v*)(Ah + a * 128 + cs * 8);
            al[rt] = *(const short8v*)(Al + a * 128 + cs * 8);
        }
        #pragma unroll
        for (int ti = 0; ti < 4; ++ti) {
            int fid = ((w + ti * 4) * 4 + ks) * 64 + l;
            short8v bh = *(const short8v*)(Bh + (size_t)fid * 8);
            short8v bl = *(const short8v*)(Bl + (size_t)fid * 8);
            #pragma unroll
            for (int rt = 0; rt < 4; ++rt) {
                acc[rt][ti] = __builtin_amdgcn_mfma_f32_16x16x32_bf16(ah[rt], bh, acc[rt][ti], 0, 0, 0);
                acc[rt][ti] = __builtin_amdgcn_mfma_f32_16x16x32_bf16(al[rt], bh, acc[rt][ti], 0, 0, 0);
                acc[rt][ti] = __builtin_amdgcn_mfma_f32_16x16x32_bf16(ah[rt], bl, acc[rt][ti], 0, 0, 0);
            }
        }
    }

    float bvz[4], scv[4], shv[4];
    #pragma unroll
    for (int ti = 0; ti < 4; ++ti) {
        int c = (w + ti * 4) * 16 + lm;
        bvz[ti] = bias[c];
        float s = bg[c] * rsqrtf(bv[c] + BN_EPS);
        scv[ti] = s;
        shv[ti] = bb[c] - bm[c] * s;
    }

    const int q = tid >> 5, cg = tid & 31;
    const int sub = blockIdx.x * 8 + q;
    const size_t slotBase = (size_t)cumSeg[sub];
    const int fs = sM[q * 8];

    #pragma unroll
    for (int hf = 0; hf < 2; ++hf) {
        __syncthreads();
        #pragma unroll
        for (int tj = 0; tj < 2; ++tj) {
            int ti = 2 * hf + tj;
            int colh = (w + ti * 4) * 16 + lm - hf * 128;
            #pragma unroll
            for (int rt = 0; rt < 4; ++rt)
                #pragma unroll
                for (int r = 0; r < 4; ++r) {
                    int row = rt * 16 + lq * 4 + r;
                    float y = fast_tanh(acc[rt][ti][r] + bvz[ti]) * scv[ti] + shv[ti];
                    Yt[row * 132 + colh] = y;
                }
        }
        __syncthreads();

        float4 ys, ym;
        int cur = sM[q * 8];
        {
            float4 v = *(const float4*)(Yt + (q * 8) * 132 + cg * 4);
            ys = v; ym = v;
        }
        #pragma unroll
        for (int i = 1; i < 8; ++i) {
            float4 v = *(const float4*)(Yt + (q * 8 + i) * 132 + cg * 4);
            int m = sM[q * 8 + i];
            if (m == cur) {
                ys.x += v.x; ys.y += v.y; ys.z += v.z; ys.w += v.w;
                ym.x = fmaxf(ym.x, v.x); ym.y = fmaxf(ym.y, v.y);
                ym.z = fmaxf(ym.z, v.z); ym.w = fmaxf(ym.w, v.w);
            } else {
                float* p = partials + (slotBase + (cur - fs)) * 512 + hf * 128 + cg * 4;
                *(float4*)p         = ys;
                *(float4*)(p + 256) = ym;
                cur = m; ys = v; ym = v;
            }
        }
        float* p = partials + (slotBase + (cur - fs)) * 512 + hf * 128 + cg * 4;
        *(float4*)p         = ys;
        *(float4*)(p + 256) = ym;
    }
}

// ---------- combine partials -> final out (tanh fused) ----------

__global__ __launch_bounds__(256)
void k_combine(const float* __restrict__ partials,
               const int* __restrict__ binBase, const int* __restrict__ binCnt,
               const int* __restrict__ firstSeg, const int* __restrict__ cumSeg,
               float* __restrict__ Out)
{
    int sid = blockIdx.x * 4 + (threadIdx.x >> 6);
    if (sid >= 40000) return;
    int lane = threadIdx.x & 63;
    int b = binBase[sid], n = binCnt[sid];

    float4 s = make_float4(0.f, 0.f, 0.f, 0.f);
    float4 m = make_float4(-INFINITY, -INFINITY, -INFINITY, -INFINITY);
    if (n > 0) {
        int s0 = b >> 3, s1 = (b + n - 1) >> 3;
        for (int t = s0; t <= s1; ++t) {
            size_t slot = (size_t)cumSeg[t] + (sid - firstSeg[t]);
            const float4* P = (const float4*)(partials + slot * 512);
            float4 a = P[lane];
            float4 x = P[64 + lane];
            s.x += a.x; s.y += a.y; s.z += a.z; s.w += a.w;
            m.x = fmaxf(m.x, x.x); m.y = fmaxf(m.y, x.y);
            m.z = fmaxf(m.z, x.z); m.w = fmaxf(m.w, x.w);
        }
    }
    float4 os = make_float4(fast_tanh(s.x), fast_tanh(s.y), fast_tanh(s.z), fast_tanh(s.w));
    float4 om = make_float4(fast_tanh(m.x), fast_tanh(m.y), fast_tanh(m.z), fast_tanh(m.w));
    *(float4*)(Out + (size_t)sid * 512 + lane * 4)       = os;
    *(float4*)(Out + (size_t)sid * 512 + 256 + lane * 4) = om;
}

// ---------- launcher ----------

extern "C" void kernel_launch(void* const* d_in, const int* in_sizes, int n_in,
                              void* d_out, int out_size, void* d_ws, size_t ws_size,
                              hipStream_t stream)
{
    const float* atom = (const float*)d_in[0];
    const int*   memb = (const int*)d_in[1];
    const int*   adj1 = (const int*)d_in[2];
    const int*   adj2 = (const int*)d_in[3];
    const int*   adj3 = (const int*)d_in[4];
    const int*   adj4 = (const int*)d_in[5];
    const float* g1Ws = (const float*)d_in[6];
    const float* g1Wr = (const float*)d_in[7];
    const float* g1b  = (const float*)d_in[8];
    const float* g2Ws = (const float*)d_in[9];
    const float* g2Wr = (const float*)d_in[10];
    const float* g2b  = (const float*)d_in[11];
    const float* bn1g = (const float*)d_in[12];
    const float* bn1b = (const float*)d_in[13];
    const float* bn1m = (const float*)d_in[14];
    const float* bn1v = (const float*)d_in[15];
    const float* bn3g = (const float*)d_in[16];
    const float* bn3b = (const float*)d_in[17];
    const float* bn3m = (const float*)d_in[18];
    const float* bn3v = (const float*)d_in[19];
    const float* dW   = (const float*)d_in[20];
    const float* db   = (const float*)d_in[21];

    char* ws = (char*)d_ws;
    float* bufA = (float*)ws;                    // [1M][128] f32, 512 MB
    float* bufB = (float*)(ws + 512000000);      // [1M][128] f32, 512 MB
    float* out  = (float*)d_out;                 // [40000][512]

    // W fragments live in d_out (only combine writes d_out, at the very end):
    ushort_t* gFh  = (ushort_t*)out;             // gc2: 18432 frags x 16B
    ushort_t* gFl  = gFh + (size_t)18432 * 8;
    ushort_t* g1Fh = gFl + (size_t)18432 * 8;    // gc1: 13824 frags x 16B
    ushort_t* g1Fl = g1Fh + (size_t)13824 * 8;   // ends ~1.03 MB << 82 MB

    // scratch inside bufA (dead after pool2 reads it):
    int* perm     = (int*)bufA;                  // 1,000,000
    int* binCnt   = perm + 1000000;              // 40,000
    int* binBase  = binCnt + 40000;
    int* binFill  = binBase + 40000;
    int* firstSeg = binFill + 40000;             // 125,000
    int* segCnt   = firstSeg + 125000;
    int* cumSeg   = segCnt + 125000;             // ends < 6 MB
    ushort_t* dWh = (ushort_t*)(ws + 6200000);   // dense: 4096 frags x 16B
    ushort_t* dWl = (ushort_t*)(ws + 6400000);
    float* partials = (float*)(ws + 8000000);    // <=164,999 slots x 512 f32 = 338 MB

    // ---- W fragment prep (into d_out; read by gc kernels, overwritten by combine) ----
    k_prepW2<<<72, 256, 0, stream>>>(g2Ws, g2Wr, gFh, gFl);
    k_prepW1<<<54, 256, 0, stream>>>(g1Ws, g1Wr, g1Fh, g1Fl);

    // ---- gc1 (MFMA, v2 staging): atom -> bufA ----
    k_gc1m<0><<<(10000 + 63) / 64, 256, 0, stream>>>(atom, nullptr,
        g1Fh + (size_t)0 * 1536 * 8, g1Fl + (size_t)0 * 1536 * 8,
        nullptr, nullptr, g1b + 0 * 128,
        bn1g, bn1b, bn1m, bn1v, bufA, 0, 10000);
    k_gc1m<1><<<(240000 + 63) / 64, 256, 0, stream>>>(atom, adj1,
        g1Fh + (size_t)1 * 1536 * 8, g1Fl + (size_t)1 * 1536 * 8,
        g1Fh + (size_t)5 * 1536 * 8, g1Fl + (size_t)5 * 1536 * 8, g1b + 1 * 128,
        bn1g, bn1b, bn1m, bn1v, bufA, 10000, 240000);
    k_gc1m<2><<<(360000 + 63) / 64, 256, 0, stream>>>(atom, adj2,
        g1Fh + (size_t)2 * 1536 * 8, g1Fl + (size_t)2 * 1536 * 8,
        g1Fh + (size_t)6 * 1536 * 8, g1Fl + (size_t)6 * 1536 * 8, g1b + 2 * 128,
        bn1g, bn1b, bn1m, bn1v, bufA, 250000, 360000);
    k_gc1m<3><<<(250000 + 63) / 64, 256, 0, stream>>>(atom, adj3,
        g1Fh + (size_t)3 * 1536 * 8, g1Fl + (size_t)3 * 1536 * 8,
        g1Fh + (size_t)7 * 1536 * 8, g1Fl + (size_t)7 * 1536 * 8, g1b + 3 * 128,
        bn1g, bn1b, bn1m, bn1v, bufA, 610000, 250000);
    k_gc1m<4><<<(140000 + 63) / 64, 256, 0, stream>>>(atom, adj4,
        g1Fh + (size_t)4 * 1536 * 8, g1Fl + (size_t)4 * 1536 * 8,
        g1Fh + (size_t)8 * 1536 * 8, g1Fl + (size_t)8 * 1536 * 8, g1b + 4 * 128,
        bn1g, bn1b, bn1m, bn1v, bufA, 860000, 140000);

    // ---- pool1: bufA -> bufB ----
    k_pool<0><<<(10000 + 7) / 8, 256, 0, stream>>>(bufA, nullptr, bufB, 0, 10000);
    k_pool<1><<<(240000 + 7) / 8, 256, 0, stream>>>(bufA, adj1, bufB, 10000, 240000);
    k_pool<2><<<(360000 + 7) / 8, 256, 0, stream>>>(bufA, adj2, bufB, 250000, 360000);
    k_pool<3><<<(250000 + 7) / 8, 256, 0, stream>>>(bufA, adj3, bufB, 610000, 250000);
    k_pool<4><<<(140000 + 7) / 8, 256, 0, stream>>>(bufA, adj4, bufB, 860000, 140000);

    // ---- gc2 (MFMA): bufB -> bufA ----
    k_gc2m<0><<<(10000 + 63) / 64, 256, 0, stream>>>(bufB, nullptr,
        gFh + (size_t)0 * 2048 * 8, gFl + (size_t)0 * 2048 * 8,
        nullptr, nullptr, g2b + 0 * 128,
        bn1g, bn1b, bn1m, bn1v, bufA, 0, 10000);
    k_gc2m<1><<<(240000 + 63) / 64, 256, 0, stream>>>(bufB, adj1,
        gFh + (size_t)1 * 2048 * 8, gFl + (size_t)1 * 2048 * 8,
        gFh + (size_t)5 * 2048 * 8, gFl + (size_t)5 * 2048 * 8, g2b + 1 * 128,
        bn1g, bn1b, bn1m, bn1v, bufA, 10000, 240000);
    k_gc2m<2><<<(360000 + 63) / 64, 256, 0, stream>>>(bufB, adj2,
        gFh + (size_t)2 * 2048 * 8, gFl + (size_t)2 * 2048 * 8,
        gFh + (size_t)6 * 2048 * 8, gFl + (size_t)6 * 2048 * 8, g2b + 2 * 128,
        bn1g, bn1b, bn1m, bn1v, bufA, 250000, 360000);
    k_gc2m<3><<<(250000 + 63) / 64, 256, 0, stream>>>(bufB, adj3,
        gFh + (size_t)3 * 2048 * 8, gFl + (size_t)3 * 2048 * 8,
        gFh + (size_t)7 * 2048 * 8, gFl + (size_t)7 * 2048 * 8, g2b + 3 * 128,
        bn1g, bn1b, bn1m, bn1v, bufA, 610000, 250000);
    k_gc2m<4><<<(140000 + 63) / 64, 256, 0, stream>>>(bufB, adj4,
        gFh + (size_t)4 * 2048 * 8, gFl + (size_t)4 * 2048 * 8,
        gFh + (size_t)8 * 2048 * 8, gFl + (size_t)8 * 2048 * 8, g2b + 4 * 128,
        bn1g, bn1b, bn1m, bn1v, bufA, 860000, 140000);

    // ---- pool2: bufA -> bufB (dense input = bufB; bufA becomes scratch) ----
    k_pool<0><<<(10000 + 7) / 8, 256, 0, stream>>>(bufA, nullptr, bufB, 0, 10000);
    k_pool<1><<<(240000 + 7) / 8, 256, 0, stream>>>(bufA, adj1, bufB, 10000, 240000);
    k_pool<2><<<(360000 + 7) / 8, 256, 0, stream>>>(bufA, adj2, bufB, 250000, 360000);
    k_pool<3><<<(250000 + 7) / 8, 256, 0, stream>>>(bufA, adj3, bufB, 610000, 250000);
    k_pool<4><<<(140000 + 7) / 8, 256, 0, stream>>>(bufA, adj4, bufB, 860000, 140000);

    // ---- counting sort by membership + subtile meta + dense W frag prep ----
    k_zero_bins<<<(40000 + 255) / 256, 256, 0, stream>>>(binCnt, binFill);
    k_hist<<<(1000000 + 255) / 256, 256, 0, stream>>>(memb, binCnt);
    k_scan<<<1, 1024, 0, stream>>>(binCnt, binBase);
    k_scatter<<<(1000000 + 255) / 256, 256, 0, stream>>>(memb, binBase, binFill, perm);
    k_meta<<<(125000 + 255) / 256, 256, 0, stream>>>(memb, perm, firstSeg, segCnt);
    k_scan2<<<1, 1024, 0, stream>>>(segCnt, cumSeg);
    k_prepW<<<16, 256, 0, stream>>>(dW, dWh, dWl);

    // ---- dense via MFMA + tanh + bn3 -> subtile partials ----
    k_dense_mfma<<<15625, 256, 0, stream>>>(bufB, memb, perm, cumSeg, dWh, dWl,
        db, bn3g, bn3b, bn3m, bn3v, partials);

    // ---- combine partials -> out (fully overwrites d_out incl. frag regions) ----
    k_combine<<<10000, 256, 0, stream>>>(partials, binBase, binCnt,
        firstSeg, cumSeg, out);
}